// Round 2
// baseline (919.081 us; speedup 1.0000x reference)
//
#include <hip/hip_runtime.h>
#include <hip/hip_bf16.h>

typedef __attribute__((ext_vector_type(8))) short short8;
typedef __attribute__((ext_vector_type(4))) float f32x4;

#define DEVINL __device__ __forceinline__

constexpr int Bc = 4, Sc = 2048, Dc = 2048, Hc = 16, DHc = 128;
constexpr float SCALE = 0.08838834764831845f;  // 1/sqrt(128)

DEVINL short f2bf(float f) {
  unsigned u = __builtin_bit_cast(unsigned, f);
  u = (u + 0x7fffu + ((u >> 16) & 1u)) >> 16;
  return (short)u;
}
DEVINL short bfc(float f) {
  __hip_bfloat16 h = __float2bfloat16(f);
  return __builtin_bit_cast(short, h);
}

// async global->LDS, 16B per lane; LDS dest = wave-uniform base + lane*16
DEVINL void gload16(const void* g, void* l) {
  __builtin_amdgcn_global_load_lds(
      (const __attribute__((address_space(1))) void*)g,
      (__attribute__((address_space(3))) void*)l, 16, 0, 0);
}

// ---------------- weight transpose + fp32->bf16:  wt[n][k] = w[k][n] -------
__global__ __launch_bounds__(256) void transpose_w_kernel(
    const float* __restrict__ w0, const float* __restrict__ w1,
    const float* __restrict__ w2, const float* __restrict__ w3,
    short* __restrict__ wt) {
  __shared__ float tile[32][33];
  const float* w = (blockIdx.z == 0) ? w0 : (blockIdx.z == 1) ? w1
                   : (blockIdx.z == 2) ? w2 : w3;
  short* out = wt + (size_t)blockIdx.z * Dc * Dc;
  int k0 = blockIdx.x * 32, n0 = blockIdx.y * 32;
  int t = threadIdx.x;
#pragma unroll
  for (int p = 0; p < 4; ++p) {
    int idx = p * 256 + t;
    int kr = idx >> 5, nc = idx & 31;
    tile[kr][nc] = w[(size_t)(k0 + kr) * Dc + n0 + nc];
  }
  __syncthreads();
#pragma unroll
  for (int p = 0; p < 4; ++p) {
    int idx = p * 256 + t;
    int nr = idx >> 5, kc = idx & 31;
    out[(size_t)(n0 + nr) * Dc + k0 + kc] = f2bf(tile[kc][nr]);
  }
}

// ---------------- GEMM: C[M,N] = A[M,K] @ Wt[N,K]^T + bias ----------------
// m97 structure: global_load_lds staging, 128x128 tile, BK=32, 2 barriers/step.
// A_IS_F32: A staged as f32 (XOR-swizzled rows), converted to bf16 at frag read.
// OUT_MODE: 0 = bf16 [M,N], 1 = f32 [M,N], 2 = bf16 V-transposed [B,H,DH,S]
template <bool A_IS_F32, int OUT_MODE>
__global__ __launch_bounds__(256) void gemm_kernel(
    const void* __restrict__ Aptr, const short* __restrict__ Wt,
    const float* __restrict__ bias, void* __restrict__ Cptr) {
  constexpr int ABYTES = A_IS_F32 ? 128 * 32 * 4 : 128 * 32 * 2;
  __shared__ __align__(16) char AsRaw[ABYTES];
  __shared__ short Bs[128 * 32];
  const int tid = threadIdx.x, lane = tid & 63, wid = tid >> 6;
  const int wm = wid >> 1, wn = wid & 1;
  const int lr = lane & 15, g = lane >> 4, lk = g * 8;
  const int m0 = blockIdx.y * 128, n0 = blockIdx.x * 128;

  f32x4 acc[4][4] = {};

  const int brow = wid * 16 + (lane >> 2), bc8 = (lane & 3) * 8;
  const int arow = wid * 8 + (lane >> 3);

  for (int k0 = 0; k0 < Dc; k0 += 32) {
    if (A_IS_F32) {
      const float* A = (const float*)Aptr;
#pragma unroll
      for (int p = 0; p < 4; ++p) {
        int row = p * 32 + arow;
        int colf = (((lane & 7) ^ (row & 7)) << 2);  // pre-swizzled source col
        gload16(&A[(size_t)(m0 + row) * Dc + k0 + colf],
                AsRaw + p * 4096 + wid * 1024);
      }
    } else {
      const short* A = (const short*)Aptr;
#pragma unroll
      for (int p = 0; p < 2; ++p) {
        gload16(&A[(size_t)(m0 + p * 64 + brow) * Dc + k0 + bc8],
                AsRaw + p * 4096 + wid * 1024);
      }
    }
#pragma unroll
    for (int p = 0; p < 2; ++p) {
      gload16(&Wt[(size_t)(n0 + p * 64 + brow) * Dc + k0 + bc8],
              (char*)Bs + p * 4096 + wid * 1024);
    }
    __syncthreads();  // drains vmcnt(0): staged tiles visible

    short8 af[4], bw[4];
    if (A_IS_F32) {
      const int xs = (lr & 7) << 4;
#pragma unroll
      for (int i = 0; i < 4; ++i) {
        const char* base = AsRaw + (size_t)(wm * 64 + i * 16 + lr) * 128;
        f32x4 a0 = *(const f32x4*)(base + ((g * 32) ^ xs));
        f32x4 a1 = *(const f32x4*)(base + ((g * 32 + 16) ^ xs));
        short8 r8;
        r8[0] = bfc(a0[0]); r8[1] = bfc(a0[1]); r8[2] = bfc(a0[2]); r8[3] = bfc(a0[3]);
        r8[4] = bfc(a1[0]); r8[5] = bfc(a1[1]); r8[6] = bfc(a1[2]); r8[7] = bfc(a1[3]);
        af[i] = r8;
      }
    } else {
      const short* As = (const short*)AsRaw;
#pragma unroll
      for (int i = 0; i < 4; ++i)
        af[i] = *(const short8*)&As[(wm * 64 + i * 16 + lr) * 32 + lk];
    }
#pragma unroll
    for (int j = 0; j < 4; ++j)
      bw[j] = *(const short8*)&Bs[(wn * 64 + j * 16 + lr) * 32 + lk];
    __syncthreads();  // all LDS reads done; next stage may overwrite

#pragma unroll
    for (int i = 0; i < 4; ++i)
#pragma unroll
      for (int j = 0; j < 4; ++j)
        acc[i][j] = __builtin_amdgcn_mfma_f32_16x16x32_bf16(af[i], bw[j], acc[i][j], 0, 0, 0);
  }

  const int rowl = g * 4;
#pragma unroll
  for (int i = 0; i < 4; ++i) {
#pragma unroll
    for (int j = 0; j < 4; ++j) {
      int gcol = n0 + wn * 64 + j * 16 + lr;
      float bv = bias[gcol];
#pragma unroll
      for (int r = 0; r < 4; ++r) {
        int grow = m0 + wm * 64 + i * 16 + rowl + r;
        float v = acc[i][j][r] + bv;
        if (OUT_MODE == 1) {
          ((float*)Cptr)[(size_t)grow * Dc + gcol] = v;
        } else if (OUT_MODE == 0) {
          ((short*)Cptr)[(size_t)grow * Dc + gcol] = f2bf(v);
        } else {
          int b4 = grow >> 11, ss = grow & (Sc - 1);
          int hh = gcol >> 7, dh = gcol & (DHc - 1);
          ((short*)Cptr)[((((size_t)(b4 * Hc + hh) * DHc) + dh) << 11) + ss] = f2bf(v);
        }
      }
    }
  }
}

// ---------------- flash attention (causal), double-buffered K/V ------------
// qp,kp: bf16 [B,S,D]; vt: bf16 [B,H,DH,S]; attn out: bf16 [B,S,D]
// K LDS tile [64][128] bf16, V tile [128][64] bf16, both XOR-swizzled:
// 16B slot index ^= (row & 7); sources pre-swizzled for linear gload_lds dest.
__global__ __launch_bounds__(256) void attn_kernel(
    const short* __restrict__ qp, const short* __restrict__ kp,
    const short* __restrict__ vt, short* __restrict__ attn) {
  __shared__ short Ks[2][64 * 128];
  __shared__ short Vs[2][128 * 64];
  __shared__ short Ps[4][16][72];
  const int tid = threadIdx.x, lane = tid & 63, wid = tid >> 6;
  const int lr = lane & 15, g = lane >> 4, lk = g * 8, rowl = g * 4;
  const int qb = ((int)gridDim.x - 1 - (int)blockIdx.x) * 64;  // longest first
  const int h = blockIdx.y, b = blockIdx.z;
  const size_t headq = ((size_t)b * Sc) * Dc + (size_t)h * DHc;
  const size_t vbase = (((size_t)b * Hc + h) * DHc) << 11;
  const int qrow0 = qb + wid * 16;

  short8 qf[4];
#pragma unroll
  for (int c = 0; c < 4; ++c)
    qf[c] = *(const short8*)&qp[headq + (size_t)(qrow0 + lr) * Dc + c * 32 + lk];

  f32x4 o[8] = {};
  float mrun[4], lrun[4];
#pragma unroll
  for (int r = 0; r < 4; ++r) { mrun[r] = -1e30f; lrun[r] = 0.f; }

  const int ntiles = qb / 64 + 1;
  const int kslot = lane & 15, vslot = lane & 7;

  auto stage = [&](int buf, int kvb) {
#pragma unroll
    for (int p = 0; p < 4; ++p) {  // K: rows of 256B
      int row = p * 16 + wid * 4 + (lane >> 4);
      int scol = ((kslot ^ (row & 7)) << 3);
      gload16(&kp[headq + (size_t)(kvb + row) * Dc + scol],
              &Ks[buf][p * 2048 + wid * 512]);
    }
#pragma unroll
    for (int p = 0; p < 4; ++p) {  // V: rows of 128B (row = dh)
      int row = p * 32 + wid * 8 + (lane >> 3);
      int scol = ((vslot ^ (row & 7)) << 3);
      gload16(&vt[vbase + (size_t)row * Sc + kvb + scol],
              &Vs[buf][p * 2048 + wid * 512]);
    }
  };

  stage(0, 0);
  __syncthreads();

  for (int t = 0; t < ntiles; ++t) {
    const int cur = t & 1;
    if (t + 1 < ntiles) stage(cur ^ 1, (t + 1) * 64);  // overlap with compute

    const short* kb = &Ks[cur][0];
    const short* vb = &Vs[cur][0];
    const int x7 = lr & 7;

    f32x4 sc[4];
    __builtin_amdgcn_s_setprio(1);
#pragma unroll
    for (int nb = 0; nb < 4; ++nb) {
      f32x4 s = {};
#pragma unroll
      for (int c = 0; c < 4; ++c) {
        short8 kf = *(const short8*)&kb[(nb * 16 + lr) * 128 + (((c * 4 + g) ^ x7) << 3)];
        s = __builtin_amdgcn_mfma_f32_16x16x32_bf16(qf[c], kf, s, 0, 0, 0);
      }
      sc[nb] = s;
    }
    __builtin_amdgcn_s_setprio(0);

    float mt[4];
#pragma unroll
    for (int r = 0; r < 4; ++r) mt[r] = -1e30f;
    if (t == ntiles - 1) {  // only the diagonal tile needs masking
#pragma unroll
      for (int nb = 0; nb < 4; ++nb) {
        int kv = t * 64 + nb * 16 + lr;
#pragma unroll
        for (int r = 0; r < 4; ++r) {
          int qr = qrow0 + rowl + r;
          float v = sc[nb][r] * SCALE;
          v = (kv > qr) ? -1e30f : v;
          sc[nb][r] = v;
          mt[r] = fmaxf(mt[r], v);
        }
      }
    } else {
#pragma unroll
      for (int nb = 0; nb < 4; ++nb)
#pragma unroll
        for (int r = 0; r < 4; ++r) {
          float v = sc[nb][r] * SCALE;
          sc[nb][r] = v;
          mt[r] = fmaxf(mt[r], v);
        }
    }
#pragma unroll
    for (int off = 1; off < 16; off <<= 1)
#pragma unroll
      for (int r = 0; r < 4; ++r) mt[r] = fmaxf(mt[r], __shfl_xor(mt[r], off));

    float alpha[4], lsum[4];
#pragma unroll
    for (int r = 0; r < 4; ++r) {
      float mnew = fmaxf(mrun[r], mt[r]);
      alpha[r] = __expf(mrun[r] - mnew);
      mrun[r] = mnew;
      lsum[r] = 0.f;
    }
#pragma unroll
    for (int nb = 0; nb < 4; ++nb)
#pragma unroll
      for (int r = 0; r < 4; ++r) {
        float p = __expf(sc[nb][r] - mrun[r]);
        lsum[r] += p;
        Ps[wid][rowl + r][nb * 16 + lr] = f2bf(p);
      }
#pragma unroll
    for (int off = 1; off < 16; off <<= 1)
#pragma unroll
      for (int r = 0; r < 4; ++r) lsum[r] += __shfl_xor(lsum[r], off);
#pragma unroll
    for (int r = 0; r < 4; ++r) lrun[r] = lrun[r] * alpha[r] + lsum[r];
#pragma unroll
    for (int f = 0; f < 8; ++f)
#pragma unroll
      for (int r = 0; r < 4; ++r) o[f][r] *= alpha[r];

    asm volatile("s_waitcnt lgkmcnt(0)" ::: "memory");
    __builtin_amdgcn_sched_barrier(0);

    __builtin_amdgcn_s_setprio(1);
#pragma unroll
    for (int kc = 0; kc < 2; ++kc) {
      short8 pf = *(const short8*)&Ps[wid][lr][kc * 32 + lk];
#pragma unroll
      for (int nb = 0; nb < 8; ++nb) {
        short8 vf = *(const short8*)&vb[(nb * 16 + lr) * 64 + (((kc * 4 + g) ^ x7) << 3)];
        o[nb] = __builtin_amdgcn_mfma_f32_16x16x32_bf16(pf, vf, o[nb], 0, 0, 0);
      }
    }
    __builtin_amdgcn_s_setprio(0);
    __syncthreads();  // drains vmcnt: next tile staged + buffers free
  }

#pragma unroll
  for (int f = 0; f < 8; ++f)
#pragma unroll
    for (int r = 0; r < 4; ++r) {
      float v = o[f][r] / lrun[r];
      attn[headq + (size_t)(qrow0 + rowl + r) * Dc + f * 16 + lr] = f2bf(v);
    }
}

// ---------------------------------------------------------------------------
extern "C" void kernel_launch(void* const* d_in, const int* in_sizes, int n_in,
                              void* d_out, int out_size, void* d_ws, size_t ws_size,
                              hipStream_t stream) {
  const float* Q = (const float*)d_in[0];
  const float* K = (const float*)d_in[1];
  const float* V = (const float*)d_in[2];
  // d_in[3] = mask (causal tril, structural — unused)
  const float* wq = (const float*)d_in[4];
  const float* bq = (const float*)d_in[5];
  const float* wk = (const float*)d_in[6];
  const float* bk = (const float*)d_in[7];
  const float* wv = (const float*)d_in[8];
  const float* bv = (const float*)d_in[9];
  const float* wo = (const float*)d_in[10];
  const float* bo = (const float*)d_in[11];

  char* ws = (char*)d_ws;
  const size_t WSZ = (size_t)Dc * Dc;
  const size_t XSZ = (size_t)Bc * Sc * Dc;
  short* WT = (short*)ws;
  short* QP = (short*)(ws + 4 * WSZ * 2);
  short* KP = (short*)(ws + 4 * WSZ * 2 + XSZ * 2);
  short* VT = (short*)(ws + 4 * WSZ * 2 + 2 * XSZ * 2);
  short* AT = (short*)(ws + 4 * WSZ * 2 + 3 * XSZ * 2);
  // total: 8*WSZ + 8*XSZ bytes = 32 MiB + 128 MiB = 160 MiB

  transpose_w_kernel<<<dim3(Dc / 32, Dc / 32, 4), 256, 0, stream>>>(wq, wk, wv, wo, WT);

  dim3 gg(Dc / 128, (Bc * Sc) / 128);  // (16, 64)
  gemm_kernel<true, 0><<<gg, 256, 0, stream>>>(Q, WT, bq, QP);
  gemm_kernel<true, 0><<<gg, 256, 0, stream>>>(K, WT + WSZ, bk, KP);
  gemm_kernel<true, 2><<<gg, 256, 0, stream>>>(V, WT + 2 * WSZ, bv, VT);

  attn_kernel<<<dim3(Sc / 64, Hc, Bc), 256, 0, stream>>>(QP, KP, VT, AT);

  gemm_kernel<false, 1><<<gg, 256, 0, stream>>>(AT, WT + 3 * WSZ, bo, (float*)d_out);
}

// Round 3
// 698.216 us; speedup vs baseline: 1.3163x; 1.3163x over previous
//
#include <hip/hip_runtime.h>
#include <hip/hip_bf16.h>

typedef __attribute__((ext_vector_type(8))) short short8;
typedef __attribute__((ext_vector_type(4))) float f32x4;

#define DEVINL __device__ __forceinline__

constexpr int Bc = 4, Sc = 2048, Dc = 2048, Hc = 16, DHc = 128;
constexpr float SCALE = 0.08838834764831845f;  // 1/sqrt(128)

DEVINL short f2bf(float f) {
  unsigned u = __builtin_bit_cast(unsigned, f);
  u = (u + 0x7fffu + ((u >> 16) & 1u)) >> 16;
  return (short)u;
}
DEVINL unsigned pack2(float a, float b) {
  return (unsigned)(unsigned short)f2bf(a) | ((unsigned)(unsigned short)f2bf(b) << 16);
}

// ---------------- weight transpose + fp32->bf16:  wt[n][k] = w[k][n] -------
__global__ __launch_bounds__(256) void transpose_w_kernel(
    const float* __restrict__ w0, const float* __restrict__ w1,
    const float* __restrict__ w2, const float* __restrict__ w3,
    short* __restrict__ wt) {
  __shared__ float tile[32][33];
  const float* w = (blockIdx.z == 0) ? w0 : (blockIdx.z == 1) ? w1
                   : (blockIdx.z == 2) ? w2 : w3;
  short* out = wt + (size_t)blockIdx.z * Dc * Dc;
  int k0 = blockIdx.x * 32, n0 = blockIdx.y * 32;
  int t = threadIdx.x;
#pragma unroll
  for (int p = 0; p < 4; ++p) {
    int idx = p * 256 + t;
    int kr = idx >> 5, nc = idx & 31;
    tile[kr][nc] = w[(size_t)(k0 + kr) * Dc + n0 + nc];
  }
  __syncthreads();
#pragma unroll
  for (int p = 0; p < 4; ++p) {
    int idx = p * 256 + t;
    int nr = idx >> 5, kc = idx & 31;
    out[(size_t)(n0 + nr) * Dc + k0 + kc] = f2bf(tile[kc][nr]);
  }
}

// ---------------- GEMM (round-1 reg-staged, known-good) --------------------
// C[M,N] = A[M,K] @ Wt[N,K]^T + bias
// OUT_MODE: 0 = bf16 [M,N], 1 = f32 [M,N], 2 = bf16 V-transposed [B,H,DH,S]
template <bool A_IS_F32, int OUT_MODE>
__global__ __launch_bounds__(256, 2) void gemm_kernel(
    const void* __restrict__ Aptr, const short* __restrict__ Wt,
    const float* __restrict__ bias, void* __restrict__ Cptr) {
  constexpr int BM = 128, BN = 128, BK = 32, PAD = 8;
  __shared__ short As[BM][BK + PAD];
  __shared__ short Bs[BN][BK + PAD];
  const int tid = threadIdx.x;
  const int lane = tid & 63, wid = tid >> 6;
  const int wm = wid >> 1, wn = wid & 1;
  const int m0 = blockIdx.y * BM, n0 = blockIdx.x * BN;
  const int lr = lane & 15, lk = (lane >> 4) * 8;

  f32x4 acc[4][4] = {};

  for (int k0 = 0; k0 < Dc; k0 += BK) {
    if (A_IS_F32) {
      const float* A = (const float*)Aptr;
      int c4 = (tid & 7) * 4;
      int rbase = tid >> 3;
#pragma unroll
      for (int p = 0; p < 4; ++p) {
        int r = rbase + p * 32;
        const f32x4 v = *(const f32x4*)&A[(size_t)(m0 + r) * Dc + k0 + c4];
        uint2 w2;
        w2.x = pack2(v[0], v[1]);
        w2.y = pack2(v[2], v[3]);
        *(uint2*)&As[r][c4] = w2;
      }
    } else {
      const short* A = (const short*)Aptr;
      int c8 = (tid & 3) * 8;
      int rbase = tid >> 2;
#pragma unroll
      for (int p = 0; p < 2; ++p) {
        int r = rbase + p * 64;
        *(short8*)&As[r][c8] = *(const short8*)&A[(size_t)(m0 + r) * Dc + k0 + c8];
      }
    }
    {
      int c8 = (tid & 3) * 8;
      int rbase = tid >> 2;
#pragma unroll
      for (int p = 0; p < 2; ++p) {
        int r = rbase + p * 64;
        *(short8*)&Bs[r][c8] = *(const short8*)&Wt[(size_t)(n0 + r) * Dc + k0 + c8];
      }
    }
    __syncthreads();
    short8 af[4], bf[4];
#pragma unroll
    for (int i = 0; i < 4; ++i) af[i] = *(const short8*)&As[wm * 64 + i * 16 + lr][lk];
#pragma unroll
    for (int j = 0; j < 4; ++j) bf[j] = *(const short8*)&Bs[wn * 64 + j * 16 + lr][lk];
#pragma unroll
    for (int i = 0; i < 4; ++i)
#pragma unroll
      for (int j = 0; j < 4; ++j)
        acc[i][j] = __builtin_amdgcn_mfma_f32_16x16x32_bf16(af[i], bf[j], acc[i][j], 0, 0, 0);
    __syncthreads();
  }

  const int rowl = (lane >> 4) * 4;
#pragma unroll
  for (int i = 0; i < 4; ++i) {
#pragma unroll
    for (int j = 0; j < 4; ++j) {
      int gcol = n0 + wn * 64 + j * 16 + lr;
      float bv = bias[gcol];
#pragma unroll
      for (int r = 0; r < 4; ++r) {
        int grow = m0 + wm * 64 + i * 16 + rowl + r;
        float v = acc[i][j][r] + bv;
        if (OUT_MODE == 1) {
          ((float*)Cptr)[(size_t)grow * Dc + gcol] = v;
        } else if (OUT_MODE == 0) {
          ((short*)Cptr)[(size_t)grow * Dc + gcol] = f2bf(v);
        } else {
          int b4 = grow >> 11, ss = grow & (Sc - 1);
          int hh = gcol >> 7, dh = gcol & (DHc - 1);
          ((short*)Cptr)[((((size_t)(b4 * Hc + hh) * DHc) + dh) << 11) + ss] = f2bf(v);
        }
      }
    }
  }
}

// ---------------- flash attention (causal) ---------------------------------
// Swapped QK^T (lane owns one q-row) + T14 async reg-staging, single-buffer.
// qp,kp: bf16 [B,S,D]; vt: bf16 [B,H,DH,S]; attn out: bf16 [B,S,D]
// LDS layout (XOR-swizzled 16B slots): Ks[row][s] = K[row][s ^ (row&7)],
// Vs[d][s] = V^T[d][s ^ (d&7)] — reads identical to round-2 (verified).
__global__ __launch_bounds__(256, 3) void attn_kernel(
    const short* __restrict__ qp, const short* __restrict__ kp,
    const short* __restrict__ vt, short* __restrict__ attn) {
  __shared__ short Ks[64 * 128];
  __shared__ short Vs[128 * 64];
  __shared__ short Ps[4][16][72];
  const int tid = threadIdx.x, lane = tid & 63, wid = tid >> 6;
  const int lr = lane & 15, g = lane >> 4, lk = g * 8, rowl = g * 4;
  const int qb = ((int)gridDim.x - 1 - (int)blockIdx.x) * 64;  // longest first
  const int h = blockIdx.y, b = blockIdx.z;
  const size_t headq = ((size_t)b * Sc) * Dc + (size_t)h * DHc;
  const size_t vbase = (((size_t)b * Hc + h) * DHc) << 11;
  const int qrow0 = qb + wid * 16;
  const int qg = qrow0 + lr;  // softmax: this lane owns q-row qg
  const int x7 = lr & 7;

  // Q fragments (used as B operand: col=lane&15=q, k contiguous)
  short8 qf[4];
#pragma unroll
  for (int c = 0; c < 4; ++c)
    qf[c] = *(const short8*)&qp[headq + (size_t)(qrow0 + lr) * Dc + c * 32 + lk];

  // staging geometry (per-thread constants)
  const int krow = wid * 4 + (lane >> 4);   // K row within 16-row group
  const int kcol = (lane & 15) * 8;         // linear source col (shorts)
  const int vrow = wid * 8 + (lane >> 3);   // V row within 32-row group
  const int vcol = (lane & 7) * 8;
  int kdst[4], vdst[4];
#pragma unroll
  for (int p = 0; p < 4; ++p) {
    kdst[p] = (p * 16 + krow) * 128 + (((lane & 15) ^ (krow & 7)) * 8);
    vdst[p] = (p * 32 + vrow) * 64 + (((lane & 7) ^ (vrow & 7)) * 8);
  }

  short8 kreg[4], vreg[4];
  auto issue = [&](int kvb) {
#pragma unroll
    for (int p = 0; p < 4; ++p)
      kreg[p] = *(const short8*)&kp[headq + (size_t)(kvb + p * 16 + krow) * Dc + kcol];
#pragma unroll
    for (int p = 0; p < 4; ++p)
      vreg[p] = *(const short8*)&vt[vbase + (size_t)(p * 32 + vrow) * Sc + kvb + vcol];
  };
  auto commit = [&]() {
#pragma unroll
    for (int p = 0; p < 4; ++p) *(short8*)&Ks[kdst[p]] = kreg[p];
#pragma unroll
    for (int p = 0; p < 4; ++p) *(short8*)&Vs[vdst[p]] = vreg[p];
  };

  issue(0);
  commit();  // compiler inserts vmcnt wait before ds_write
  __syncthreads();

  f32x4 o[8] = {};
  float mrun = -1e30f, lrun = 0.f;
  const int ntiles = qb / 64 + 1;

  for (int t = 0; t < ntiles; ++t) {
    // ---- QK^T swapped: sc[nb] holds S^T — lane owns q=qg, kv=nb*16+rowl+r
    f32x4 sc[4];
    __builtin_amdgcn_s_setprio(1);
#pragma unroll
    for (int nb = 0; nb < 4; ++nb) {
      f32x4 s = {};
#pragma unroll
      for (int c = 0; c < 4; ++c) {
        short8 kf = *(const short8*)&Ks[(nb * 16 + lr) * 128 + (((c * 4 + g) ^ x7) << 3)];
        s = __builtin_amdgcn_mfma_f32_16x16x32_bf16(kf, qf[c], s, 0, 0, 0);
      }
      sc[nb] = s;
    }
    __builtin_amdgcn_s_setprio(0);

    // ---- prefetch next K/V tile into registers (latency hides under softmax+PV)
    if (t + 1 < ntiles) issue((t + 1) * 64);

    // ---- scale + mask + row max (scalar per lane)
    float mnb[4];
    if (t == ntiles - 1) {  // diagonal tile
#pragma unroll
      for (int nb = 0; nb < 4; ++nb) {
#pragma unroll
        for (int r = 0; r < 4; ++r) {
          int kv = t * 64 + nb * 16 + rowl + r;
          float v = sc[nb][r] * SCALE;
          v = (kv > qg) ? -1e30f : v;
          sc[nb][r] = v;
        }
        mnb[nb] = fmaxf(fmaxf(sc[nb][0], sc[nb][1]), fmaxf(sc[nb][2], sc[nb][3]));
      }
    } else {
#pragma unroll
      for (int nb = 0; nb < 4; ++nb) {
#pragma unroll
        for (int r = 0; r < 4; ++r) sc[nb][r] *= SCALE;
        mnb[nb] = fmaxf(fmaxf(sc[nb][0], sc[nb][1]), fmaxf(sc[nb][2], sc[nb][3]));
      }
    }
    float mt = fmaxf(fmaxf(mnb[0], mnb[1]), fmaxf(mnb[2], mnb[3]));
    mt = fmaxf(mt, __shfl_xor(mt, 16));
    mt = fmaxf(mt, __shfl_xor(mt, 32));

    float mnew = fmaxf(mrun, mt);
    float alpha = __expf(mrun - mnew);
    mrun = mnew;

    // ---- exp + packed P write (4x ds_write_b64 per lane)
    float lsnb[4];
#pragma unroll
    for (int nb = 0; nb < 4; ++nb) {
      float p0 = __expf(sc[nb][0] - mrun);
      float p1 = __expf(sc[nb][1] - mrun);
      float p2 = __expf(sc[nb][2] - mrun);
      float p3 = __expf(sc[nb][3] - mrun);
      lsnb[nb] = (p0 + p1) + (p2 + p3);
      uint2 w;
      w.x = pack2(p0, p1);
      w.y = pack2(p2, p3);
      *(uint2*)&Ps[wid][lr][nb * 16 + rowl] = w;
    }
    float ls = (lsnb[0] + lsnb[1]) + (lsnb[2] + lsnb[3]);
    ls += __shfl_xor(ls, 16);
    ls += __shfl_xor(ls, 32);
    lrun = lrun * alpha + ls;

    // ---- rescale O (alpha for q=rowl+r lives at lane (group | rowl+r))
    float al[4];
#pragma unroll
    for (int r = 0; r < 4; ++r) al[r] = __shfl(alpha, (lane & 48) | (rowl + r));
#pragma unroll
    for (int f = 0; f < 8; ++f)
#pragma unroll
      for (int r = 0; r < 4; ++r) o[f][r] *= al[r];

    asm volatile("s_waitcnt lgkmcnt(0)" ::: "memory");
    __builtin_amdgcn_sched_barrier(0);

    // ---- PV
    __builtin_amdgcn_s_setprio(1);
#pragma unroll
    for (int kc = 0; kc < 2; ++kc) {
      short8 pf = *(const short8*)&Ps[wid][lr][kc * 32 + lk];
#pragma unroll
      for (int nb = 0; nb < 8; ++nb) {
        short8 vf = *(const short8*)&Vs[(nb * 16 + lr) * 64 + (((kc * 4 + g) ^ x7) << 3)];
        o[nb] = __builtin_amdgcn_mfma_f32_16x16x32_bf16(pf, vf, o[nb], 0, 0, 0);
      }
    }
    __builtin_amdgcn_s_setprio(0);

    __syncthreads();                       // all Ks/Vs reads of tile t done
    if (t + 1 < ntiles) commit();          // vmcnt auto-wait + ds_write
    __syncthreads();                       // tile t+1 visible
  }

  float ld[4];
#pragma unroll
  for (int r = 0; r < 4; ++r) ld[r] = __shfl(lrun, (lane & 48) | (rowl + r));
#pragma unroll
  for (int f = 0; f < 8; ++f)
#pragma unroll
    for (int r = 0; r < 4; ++r) {
      float v = o[f][r] / ld[r];
      attn[headq + (size_t)(qrow0 + rowl + r) * Dc + f * 16 + lr] = f2bf(v);
    }
}

// ---------------------------------------------------------------------------
extern "C" void kernel_launch(void* const* d_in, const int* in_sizes, int n_in,
                              void* d_out, int out_size, void* d_ws, size_t ws_size,
                              hipStream_t stream) {
  const float* Q = (const float*)d_in[0];
  const float* K = (const float*)d_in[1];
  const float* V = (const float*)d_in[2];
  // d_in[3] = mask (causal tril, structural — unused)
  const float* wq = (const float*)d_in[4];
  const float* bq = (const float*)d_in[5];
  const float* wk = (const float*)d_in[6];
  const float* bk = (const float*)d_in[7];
  const float* wv = (const float*)d_in[8];
  const float* bv = (const float*)d_in[9];
  const float* wo = (const float*)d_in[10];
  const float* bo = (const float*)d_in[11];

  char* ws = (char*)d_ws;
  const size_t WSZ = (size_t)Dc * Dc;
  const size_t XSZ = (size_t)Bc * Sc * Dc;
  short* WT = (short*)ws;
  short* QP = (short*)(ws + 4 * WSZ * 2);
  short* KP = (short*)(ws + 4 * WSZ * 2 + XSZ * 2);
  short* VT = (short*)(ws + 4 * WSZ * 2 + 2 * XSZ * 2);
  short* AT = (short*)(ws + 4 * WSZ * 2 + 3 * XSZ * 2);
  // total: 8*WSZ + 8*XSZ bytes = 32 MiB + 128 MiB = 160 MiB

  transpose_w_kernel<<<dim3(Dc / 32, Dc / 32, 4), 256, 0, stream>>>(wq, wk, wv, wo, WT);

  dim3 gg(Dc / 128, (Bc * Sc) / 128);  // (16, 64)
  gemm_kernel<true, 0><<<gg, 256, 0, stream>>>(Q, WT, bq, QP);
  gemm_kernel<true, 0><<<gg, 256, 0, stream>>>(K, WT + WSZ, bk, KP);
  gemm_kernel<true, 2><<<gg, 256, 0, stream>>>(V, WT + 2 * WSZ, bv, VT);

  attn_kernel<<<dim3(Sc / 64, Hc, Bc), 256, 0, stream>>>(QP, KP, VT, AT);

  gemm_kernel<false, 1><<<gg, 256, 0, stream>>>(AT, WT + 3 * WSZ, bo, (float*)d_out);
}

// Round 4
// 664.228 us; speedup vs baseline: 1.3837x; 1.0512x over previous
//
#include <hip/hip_runtime.h>
#include <hip/hip_bf16.h>

typedef __attribute__((ext_vector_type(8))) short short8;
typedef __attribute__((ext_vector_type(4))) float f32x4;

#define DEVINL __device__ __forceinline__

constexpr int Bc = 4, Sc = 2048, Dc = 2048, Hc = 16, DHc = 128;
constexpr float SCALE = 0.08838834764831845f;  // 1/sqrt(128)

DEVINL short f2bf(float f) {
  unsigned u = __builtin_bit_cast(unsigned, f);
  u = (u + 0x7fffu + ((u >> 16) & 1u)) >> 16;
  return (short)u;
}
DEVINL unsigned pack2(float a, float b) {
  return (unsigned)(unsigned short)f2bf(a) | ((unsigned)(unsigned short)f2bf(b) << 16);
}

// async global->LDS, 16B per lane; LDS dest = wave-uniform base + lane*16
DEVINL void gload16(const void* g, void* l) {
  __builtin_amdgcn_global_load_lds(
      (const __attribute__((address_space(1))) void*)g,
      (__attribute__((address_space(3))) void*)l, 16, 0, 0);
}

// ---------------- weight transpose + fp32->bf16:  wt[n][k] = w[k][n] -------
__global__ __launch_bounds__(256) void transpose_w_kernel(
    const float* __restrict__ w0, const float* __restrict__ w1,
    const float* __restrict__ w2, const float* __restrict__ w3,
    short* __restrict__ wt) {
  __shared__ float tile[32][33];
  const float* w = (blockIdx.z == 0) ? w0 : (blockIdx.z == 1) ? w1
                   : (blockIdx.z == 2) ? w2 : w3;
  short* out = wt + (size_t)blockIdx.z * Dc * Dc;
  int k0 = blockIdx.x * 32, n0 = blockIdx.y * 32;
  int t = threadIdx.x;
#pragma unroll
  for (int p = 0; p < 4; ++p) {
    int idx = p * 256 + t;
    int kr = idx >> 5, nc = idx & 31;
    tile[kr][nc] = w[(size_t)(k0 + kr) * Dc + n0 + nc];
  }
  __syncthreads();
#pragma unroll
  for (int p = 0; p < 4; ++p) {
    int idx = p * 256 + t;
    int nr = idx >> 5, kc = idx & 31;
    out[(size_t)(n0 + nr) * Dc + k0 + kc] = f2bf(tile[kc][nr]);
  }
}

// ---------------- f32 -> bf16 convert (vectorized, grid-stride) ------------
__global__ __launch_bounds__(256) void convert_kernel(
    const float* __restrict__ in, short* __restrict__ out, int n8) {
  int stride = gridDim.x * 256;
  for (int idx = blockIdx.x * 256 + threadIdx.x; idx < n8; idx += stride) {
    const f32x4* p = (const f32x4*)(in + (size_t)idx * 8);
    f32x4 a = p[0], b = p[1];
    short8 r;
    r[0] = f2bf(a[0]); r[1] = f2bf(a[1]); r[2] = f2bf(a[2]); r[3] = f2bf(a[3]);
    r[4] = f2bf(b[0]); r[5] = f2bf(b[1]); r[6] = f2bf(b[2]); r[7] = f2bf(b[3]);
    *(short8*)(out + (size_t)idx * 8) = r;
  }
}

// ---------------- GEMM (m97 structure): C = A[M,K] @ Wt[N,K]^T + bias ------
// A bf16. global_load_lds w=16 staging, 128x128 tile, BK=32, linear LDS,
// XCD-aware bijective block swizzle (1024 blocks, 8 XCDs).
// OUT_MODE: 0 = bf16 [M,N], 1 = f32 [M,N], 2 = bf16 V-transposed [B,H,DH,S]
template <int OUT_MODE>
__global__ __launch_bounds__(256) void gemm_kernel(
    const short* __restrict__ A, const short* __restrict__ Wt,
    const float* __restrict__ bias, void* __restrict__ Cptr) {
  __shared__ __align__(16) short As[128 * 32];
  __shared__ __align__(16) short Bs[128 * 32];
  const int tid = threadIdx.x, lane = tid & 63, wid = tid >> 6;
  const int wm = wid >> 1, wn = wid & 1;
  const int lr = lane & 15, g = lane >> 4, lk = g * 8;

  // XCD swizzle: consecutive swz ids share A-panels within one XCD's L2
  const int bid = blockIdx.y * gridDim.x + blockIdx.x;  // 0..1023
  const int swz = (bid & 7) * 128 + (bid >> 3);
  const int m0 = (swz >> 4) * 128, n0 = (swz & 15) * 128;

  const int srow = wid * 16 + (lane >> 2);  // 0..63
  const int scol = (lane & 3) * 8;
  const size_t abase = (size_t)(m0 + srow) * Dc + scol;
  const size_t bbase = (size_t)(n0 + srow) * Dc + scol;
  char* asl = (char*)As + wid * 1024;
  char* bsl = (char*)Bs + wid * 1024;

  f32x4 acc[4][4] = {};

  for (int k0 = 0; k0 < Dc; k0 += 32) {
    gload16(&A[abase + k0], asl);
    gload16(&A[abase + (size_t)64 * Dc + k0], asl + 4096);
    gload16(&Wt[bbase + k0], bsl);
    gload16(&Wt[bbase + (size_t)64 * Dc + k0], bsl + 4096);
    __syncthreads();  // drains vmcnt(0): tiles visible

    short8 af[4], bf[4];
#pragma unroll
    for (int i = 0; i < 4; ++i)
      af[i] = *(const short8*)&As[(wm * 64 + i * 16 + lr) * 32 + lk];
#pragma unroll
    for (int j = 0; j < 4; ++j)
      bf[j] = *(const short8*)&Bs[(wn * 64 + j * 16 + lr) * 32 + lk];
#pragma unroll
    for (int i = 0; i < 4; ++i)
#pragma unroll
      for (int j = 0; j < 4; ++j)
        acc[i][j] = __builtin_amdgcn_mfma_f32_16x16x32_bf16(af[i], bf[j], acc[i][j], 0, 0, 0);
    __syncthreads();  // LDS reads done; next stage may overwrite
  }

  const int rowl = g * 4;
#pragma unroll
  for (int i = 0; i < 4; ++i) {
#pragma unroll
    for (int j = 0; j < 4; ++j) {
      int gcol = n0 + wn * 64 + j * 16 + lr;
      float bv = bias[gcol];
#pragma unroll
      for (int r = 0; r < 4; ++r) {
        int grow = m0 + wm * 64 + i * 16 + rowl + r;
        float v = acc[i][j][r] + bv;
        if (OUT_MODE == 1) {
          ((float*)Cptr)[(size_t)grow * Dc + gcol] = v;
        } else if (OUT_MODE == 0) {
          ((short*)Cptr)[(size_t)grow * Dc + gcol] = f2bf(v);
        } else {
          int b4 = grow >> 11, ss = grow & (Sc - 1);
          int hh = gcol >> 7, dh = gcol & (DHc - 1);
          ((short*)Cptr)[((((size_t)(b4 * Hc + hh) * DHc) + dh) << 11) + ss] = f2bf(v);
        }
      }
    }
  }
}

// ---------------- flash attention (causal), QB=128 (32 q-rows/wave) --------
// Swapped QK^T (lane owns q-rows) + T14 async reg-staging, single-buffer.
// qp,kp: bf16 [B,S,D]; vt: bf16 [B,H,DH,S]; attn out: bf16 [B,S,D]
// LDS XOR-swizzled 16B slots: Ks[row][s^=(row&7)], Vs[d][s^=(d&7)].
__global__ __launch_bounds__(256, 2) void attn_kernel(
    const short* __restrict__ qp, const short* __restrict__ kp,
    const short* __restrict__ vt, short* __restrict__ attn) {
  __shared__ __align__(16) short Ks[64 * 128];
  __shared__ __align__(16) short Vs[128 * 64];
  __shared__ __align__(16) short Ps[4][32][72];
  const int tid = threadIdx.x, lane = tid & 63, wid = tid >> 6;
  const int lr = lane & 15, g = lane >> 4, lk = g * 8, rowl = g * 4;
  const int qb = ((int)gridDim.x - 1 - (int)blockIdx.x) * 128;  // longest first
  const int h = blockIdx.y, b = blockIdx.z;
  const size_t headq = ((size_t)b * Sc) * Dc + (size_t)h * DHc;
  const size_t vbase = (((size_t)b * Hc + h) * DHc) << 11;
  const int qw = qb + wid * 32;  // this wave's first q-row
  const int x7 = lr & 7;

  // Q fragments (B operand: col=lane&15=q-local, k contiguous)
  short8 qf[2][4];
#pragma unroll
  for (int qs = 0; qs < 2; ++qs)
#pragma unroll
    for (int c = 0; c < 4; ++c)
      qf[qs][c] = *(const short8*)&qp[headq + (size_t)(qw + qs * 16 + lr) * Dc + c * 32 + lk];

  // staging geometry
  const int krow = wid * 4 + g;
  const int kcol = lr * 8;
  const int vrow = wid * 8 + (lane >> 3);
  const int vcol = (lane & 7) * 8;
  int kdst[4], vdst[4];
#pragma unroll
  for (int p = 0; p < 4; ++p) {
    kdst[p] = (p * 16 + krow) * 128 + ((lr ^ (krow & 7)) * 8);
    vdst[p] = (p * 32 + vrow) * 64 + (((lane & 7) ^ (vrow & 7)) * 8);
  }

  short8 kreg[4], vreg[4];
  auto issue = [&](int kvb) {
#pragma unroll
    for (int p = 0; p < 4; ++p)
      kreg[p] = *(const short8*)&kp[headq + (size_t)(kvb + p * 16 + krow) * Dc + kcol];
#pragma unroll
    for (int p = 0; p < 4; ++p)
      vreg[p] = *(const short8*)&vt[vbase + (size_t)(p * 32 + vrow) * Sc + kvb + vcol];
  };
  auto commit = [&]() {
#pragma unroll
    for (int p = 0; p < 4; ++p) *(short8*)&Ks[kdst[p]] = kreg[p];
#pragma unroll
    for (int p = 0; p < 4; ++p) *(short8*)&Vs[vdst[p]] = vreg[p];
  };

  issue(0);
  commit();
  __syncthreads();

  f32x4 o[2][8] = {};
  float mrun[2] = {-1e30f, -1e30f}, lrun[2] = {0.f, 0.f};
  const int ntiles = qb / 64 + 2;

  for (int t = 0; t < ntiles; ++t) {
    const bool active = (64 * t <= qw + 31);  // wave-uniform
    f32x4 sc[2][4];

    if (active) {
      __builtin_amdgcn_s_setprio(1);
#pragma unroll
      for (int nb = 0; nb < 4; ++nb) {
        f32x4 s0 = {}, s1 = {};
#pragma unroll
        for (int c = 0; c < 4; ++c) {
          short8 kf = *(const short8*)&Ks[(nb * 16 + lr) * 128 + (((c * 4 + g) ^ x7) << 3)];
          s0 = __builtin_amdgcn_mfma_f32_16x16x32_bf16(kf, qf[0][c], s0, 0, 0, 0);
          s1 = __builtin_amdgcn_mfma_f32_16x16x32_bf16(kf, qf[1][c], s1, 0, 0, 0);
        }
        sc[0][nb] = s0;
        sc[1][nb] = s1;
      }
      __builtin_amdgcn_s_setprio(0);
    }

    if (t + 1 < ntiles) issue((t + 1) * 64);  // prefetch hides under softmax+PV

    if (active) {
      const bool domask = (64 * t + 63 > qw);
#pragma unroll
      for (int qs = 0; qs < 2; ++qs) {
        const int qg = qw + qs * 16 + lr;
        float mnb[4];
#pragma unroll
        for (int nb = 0; nb < 4; ++nb) {
#pragma unroll
          for (int r = 0; r < 4; ++r) {
            float v = sc[qs][nb][r] * SCALE;
            if (domask) {
              int kv = t * 64 + nb * 16 + rowl + r;
              v = (kv > qg) ? -1e30f : v;
            }
            sc[qs][nb][r] = v;
          }
          mnb[nb] = fmaxf(fmaxf(sc[qs][nb][0], sc[qs][nb][1]),
                          fmaxf(sc[qs][nb][2], sc[qs][nb][3]));
        }
        float mt = fmaxf(fmaxf(mnb[0], mnb[1]), fmaxf(mnb[2], mnb[3]));
        mt = fmaxf(mt, __shfl_xor(mt, 16));
        mt = fmaxf(mt, __shfl_xor(mt, 32));

        float mnew = fmaxf(mrun[qs], mt);
        float alpha = __expf(mrun[qs] - mnew);
        mrun[qs] = mnew;

        float lsnb[4];
#pragma unroll
        for (int nb = 0; nb < 4; ++nb) {
          float p0 = __expf(sc[qs][nb][0] - mnew);
          float p1 = __expf(sc[qs][nb][1] - mnew);
          float p2 = __expf(sc[qs][nb][2] - mnew);
          float p3 = __expf(sc[qs][nb][3] - mnew);
          lsnb[nb] = (p0 + p1) + (p2 + p3);
          uint2 w;
          w.x = pack2(p0, p1);
          w.y = pack2(p2, p3);
          *(uint2*)&Ps[wid][qs * 16 + lr][nb * 16 + rowl] = w;
        }
        float ls = (lsnb[0] + lsnb[1]) + (lsnb[2] + lsnb[3]);
        ls += __shfl_xor(ls, 16);
        ls += __shfl_xor(ls, 32);
        lrun[qs] = lrun[qs] * alpha + ls;

        float al[4];
#pragma unroll
        for (int r = 0; r < 4; ++r) al[r] = __shfl(alpha, (lane & 48) | (rowl + r));
#pragma unroll
        for (int f = 0; f < 8; ++f)
#pragma unroll
          for (int r = 0; r < 4; ++r) o[qs][f][r] *= al[r];
      }

      asm volatile("s_waitcnt lgkmcnt(0)" ::: "memory");
      __builtin_amdgcn_sched_barrier(0);

      __builtin_amdgcn_s_setprio(1);
#pragma unroll
      for (int kc = 0; kc < 2; ++kc) {
        short8 pf0 = *(const short8*)&Ps[wid][lr][kc * 32 + lk];
        short8 pf1 = *(const short8*)&Ps[wid][16 + lr][kc * 32 + lk];
#pragma unroll
        for (int nb = 0; nb < 8; ++nb) {
          short8 vf = *(const short8*)&Vs[(nb * 16 + lr) * 64 + (((kc * 4 + g) ^ x7) << 3)];
          o[0][nb] = __builtin_amdgcn_mfma_f32_16x16x32_bf16(pf0, vf, o[0][nb], 0, 0, 0);
          o[1][nb] = __builtin_amdgcn_mfma_f32_16x16x32_bf16(pf1, vf, o[1][nb], 0, 0, 0);
        }
      }
      __builtin_amdgcn_s_setprio(0);
    }

    __syncthreads();               // all Ks/Vs reads of tile t done
    if (t + 1 < ntiles) commit();  // vmcnt auto-wait + ds_write
    __syncthreads();               // tile t+1 visible
  }

#pragma unroll
  for (int qs = 0; qs < 2; ++qs) {
    float ld[4];
#pragma unroll
    for (int r = 0; r < 4; ++r) ld[r] = __shfl(lrun[qs], (lane & 48) | (rowl + r));
#pragma unroll
    for (int f = 0; f < 8; ++f)
#pragma unroll
      for (int r = 0; r < 4; ++r) {
        float v = o[qs][f][r] / ld[r];
        attn[headq + (size_t)(qw + qs * 16 + rowl + r) * Dc + f * 16 + lr] = f2bf(v);
      }
  }
}

// ---------------------------------------------------------------------------
extern "C" void kernel_launch(void* const* d_in, const int* in_sizes, int n_in,
                              void* d_out, int out_size, void* d_ws, size_t ws_size,
                              hipStream_t stream) {
  const float* Q = (const float*)d_in[0];
  const float* K = (const float*)d_in[1];
  const float* V = (const float*)d_in[2];
  // d_in[3] = mask (causal tril, structural — unused)
  const float* wq = (const float*)d_in[4];
  const float* bq = (const float*)d_in[5];
  const float* wk = (const float*)d_in[6];
  const float* bk = (const float*)d_in[7];
  const float* wv = (const float*)d_in[8];
  const float* bv = (const float*)d_in[9];
  const float* wo = (const float*)d_in[10];
  const float* bo = (const float*)d_in[11];

  char* ws = (char*)d_ws;
  const size_t WSZ = (size_t)Dc * Dc;
  const size_t XSZ = (size_t)Bc * Sc * Dc;
  short* WT = (short*)ws;
  short* QP = (short*)(ws + 4 * WSZ * 2);
  short* KP = (short*)(ws + 4 * WSZ * 2 + XSZ * 2);
  short* VT = (short*)(ws + 4 * WSZ * 2 + 2 * XSZ * 2);
  short* AT = (short*)(ws + 4 * WSZ * 2 + 3 * XSZ * 2);  // scratch: conv in, attn out
  // total: 8*WSZ + 8*XSZ bytes = 32 MiB + 128 MiB = 160 MiB

  transpose_w_kernel<<<dim3(Dc / 32, Dc / 32, 4), 256, 0, stream>>>(wq, wk, wv, wo, WT);

  const int n8 = (int)(XSZ / 8);
  dim3 gg(Dc / 128, (Bc * Sc) / 128);  // (16, 64) = 1024 blocks

  convert_kernel<<<2048, 256, 0, stream>>>(Q, AT, n8);
  gemm_kernel<0><<<gg, 256, 0, stream>>>(AT, WT, bq, QP);
  convert_kernel<<<2048, 256, 0, stream>>>(K, AT, n8);
  gemm_kernel<0><<<gg, 256, 0, stream>>>(AT, WT + WSZ, bk, KP);
  convert_kernel<<<2048, 256, 0, stream>>>(V, AT, n8);
  gemm_kernel<2><<<gg, 256, 0, stream>>>(AT, WT + 2 * WSZ, bv, VT);

  attn_kernel<<<dim3(Sc / 128, Hc, Bc), 256, 0, stream>>>(QP, KP, VT, AT);

  gemm_kernel<1><<<gg, 256, 0, stream>>>(AT, WT + 3 * WSZ, bo, (float*)d_out);
}

// Round 5
// 604.737 us; speedup vs baseline: 1.5198x; 1.0984x over previous
//
#include <hip/hip_runtime.h>
#include <hip/hip_bf16.h>

typedef __attribute__((ext_vector_type(8))) short short8;
typedef __attribute__((ext_vector_type(4))) float f32x4;

#define DEVINL __device__ __forceinline__

constexpr int Bc = 4, Sc = 2048, Dc = 2048, Hc = 16, DHc = 128;
constexpr float SCALE = 0.08838834764831845f;  // 1/sqrt(128)

DEVINL short f2bf(float f) {
  unsigned u = __builtin_bit_cast(unsigned, f);
  u = (u + 0x7fffu + ((u >> 16) & 1u)) >> 16;
  return (short)u;
}
DEVINL unsigned pack2(float a, float b) {
  return (unsigned)(unsigned short)f2bf(a) | ((unsigned)(unsigned short)f2bf(b) << 16);
}

// async global->LDS, 16B per lane; LDS dest = wave-uniform base + lane*16
DEVINL void gload16(const void* g, void* l) {
  __builtin_amdgcn_global_load_lds(
      (const __attribute__((address_space(1))) void*)g,
      (__attribute__((address_space(3))) void*)l, 16, 0, 0);
}

// ---------------- weight transpose + fp32->bf16:  wt[n][k] = w[k][n] -------
__global__ __launch_bounds__(256) void transpose_w_kernel(
    const float* __restrict__ w0, const float* __restrict__ w1,
    const float* __restrict__ w2, const float* __restrict__ w3,
    short* __restrict__ wt) {
  __shared__ float tile[32][33];
  const float* w = (blockIdx.z == 0) ? w0 : (blockIdx.z == 1) ? w1
                   : (blockIdx.z == 2) ? w2 : w3;
  short* out = wt + (size_t)blockIdx.z * Dc * Dc;
  int k0 = blockIdx.x * 32, n0 = blockIdx.y * 32;
  int t = threadIdx.x;
#pragma unroll
  for (int p = 0; p < 4; ++p) {
    int idx = p * 256 + t;
    int kr = idx >> 5, nc = idx & 31;
    tile[kr][nc] = w[(size_t)(k0 + kr) * Dc + n0 + nc];
  }
  __syncthreads();
#pragma unroll
  for (int p = 0; p < 4; ++p) {
    int idx = p * 256 + t;
    int nr = idx >> 5, kc = idx & 31;
    out[(size_t)(n0 + nr) * Dc + k0 + kc] = f2bf(tile[kc][nr]);
  }
}

// ---------------- f32 -> bf16 convert (vectorized, grid-stride) ------------
__global__ __launch_bounds__(256) void convert_kernel(
    const float* __restrict__ in, short* __restrict__ out, int n8) {
  int stride = gridDim.x * 256;
  for (int idx = blockIdx.x * 256 + threadIdx.x; idx < n8; idx += stride) {
    const f32x4* p = (const f32x4*)(in + (size_t)idx * 8);
    f32x4 a = p[0], b = p[1];
    short8 r;
    r[0] = f2bf(a[0]); r[1] = f2bf(a[1]); r[2] = f2bf(a[2]); r[3] = f2bf(a[3]);
    r[4] = f2bf(b[0]); r[5] = f2bf(b[1]); r[6] = f2bf(b[2]); r[7] = f2bf(b[3]);
    *(short8*)(out + (size_t)idx * 8) = r;
  }
}

// ---------------- 256x256 8-phase GEMM: C = A[M,K] @ Wt[N,K]^T + bias ------
// 8 waves (2M x 4N), BK=64, LDS = 2 K-tile slots per tensor (128 KiB).
// slot(kt) = kt&1. Iteration t: phases 0-3 compute kt=2t (slot0), 4-7 kt=2t+1
// (slot1). Stage kt2t+1 issued at (half0,q0) [slot1 free since last iter],
// kt2t+2 at (half1,q0) [slot0 reads done at half0-q3, barrier-ordered].
// vmcnt(0) at each q3 lands ~3 phases (~900cy) after issue -> near-free drain.
// LDS 16B-slot XOR swizzle (slot ^= row&7): 2-way max conflicts (free).
// OUT_MODE: 0 = bf16 [M,N], 1 = f32 [M,N], 2 = bf16 V-transposed [B,H,DH,S]
template <int OUT_MODE>
__global__ __launch_bounds__(512, 2) void gemm256_kernel(
    const short* __restrict__ A, const short* __restrict__ Wt,
    const float* __restrict__ bias, void* __restrict__ Cptr) {
  __shared__ __align__(16) short As[2][256 * 64];
  __shared__ __align__(16) short Bs[2][256 * 64];
  const int tid = threadIdx.x, lane = tid & 63, wid = tid >> 6;
  const int wm = wid >> 2, wn = wid & 3;
  const int lr = lane & 15, g = lane >> 4, x7 = lr & 7;

  // XCD-aware bijective swizzle: 256 blocks, 8 XCDs, 32 per XCD
  const int bid = blockIdx.x;
  const int swz = (bid & 7) * 32 + (bid >> 3);
  const int m0 = (swz >> 3) * 256, n0 = (swz & 7) * 256;

  // staging geometry: wave w covers rows w*8..w*8+7 per 64-row group
  const int srow8 = lane >> 3;                 // 0..7
  const int scol = ((lane & 7) ^ srow8) * 8;   // pre-swizzled source col
  const int arow = m0 + wid * 8 + srow8;
  const int brow = n0 + wid * 8 + srow8;
  const int ldst = wid * 8 * 128;              // bytes

  auto stageKt = [&](int kt, int slot) {
    const int kof = kt * 64 + scol;
#pragma unroll
    for (int h = 0; h < 2; ++h)
#pragma unroll
      for (int p2 = 0; p2 < 2; ++p2) {
        const int roff = h * 128 + p2 * 64;
        gload16(&A[(size_t)(arow + roff) * Dc + kof],
                (char*)&As[slot][0] + roff * 128 + ldst);
        gload16(&Wt[(size_t)(brow + roff) * Dc + kof],
                (char*)&Bs[slot][0] + roff * 128 + ldst);
      }
  };

  f32x4 acc[8][4] = {};

  stageKt(0, 0);
  asm volatile("s_waitcnt vmcnt(0)" ::: "memory");
  __builtin_amdgcn_s_barrier();

  for (int t = 0; t < 16; ++t) {
#pragma unroll
    for (int half = 0; half < 2; ++half) {
      const short* Ab = &As[half][0];
      const short* Bb = &Bs[half][0];
      short8 afr[4][2], bfr[4][2];
#pragma unroll
      for (int q = 0; q < 4; ++q) {
        // ---- fragment ds_reads for this phase (reuse across quadrants)
        if (q == 0) {
#pragma unroll
          for (int i = 0; i < 4; ++i)
#pragma unroll
            for (int kk = 0; kk < 2; ++kk)
              afr[i][kk] = *(const short8*)&Ab[(wm * 128 + i * 16 + lr) * 64 +
                                               (((kk * 4 + g) ^ x7) * 8)];
#pragma unroll
          for (int j = 0; j < 2; ++j)
#pragma unroll
            for (int kk = 0; kk < 2; ++kk)
              bfr[j][kk] = *(const short8*)&Bb[(wn * 64 + j * 16 + lr) * 64 +
                                               (((kk * 4 + g) ^ x7) * 8)];
        } else if (q == 1) {
#pragma unroll
          for (int j = 2; j < 4; ++j)
#pragma unroll
            for (int kk = 0; kk < 2; ++kk)
              bfr[j][kk] = *(const short8*)&Bb[(wn * 64 + j * 16 + lr) * 64 +
                                               (((kk * 4 + g) ^ x7) * 8)];
        } else if (q == 2) {
#pragma unroll
          for (int i = 0; i < 4; ++i)
#pragma unroll
            for (int kk = 0; kk < 2; ++kk)
              afr[i][kk] = *(const short8*)&Ab[(wm * 128 + 64 + i * 16 + lr) * 64 +
                                               (((kk * 4 + g) ^ x7) * 8)];
        }
        // ---- staging issue (early in the slot's free window)
        if (q == 0) {
          if (half == 0) stageKt(2 * t + 1, 1);
          else if (t < 15) stageKt(2 * t + 2, 0);
        }
        __builtin_amdgcn_s_barrier();
        asm volatile("s_waitcnt lgkmcnt(0)" ::: "memory");
        __builtin_amdgcn_sched_barrier(0);
        // ---- 16 MFMA: one C-quadrant x K=64
        __builtin_amdgcn_s_setprio(1);
        const int qr = q >> 1, qc = q & 1;
#pragma unroll
        for (int i = 0; i < 4; ++i)
#pragma unroll
          for (int j = 0; j < 2; ++j)
#pragma unroll
            for (int kk = 0; kk < 2; ++kk)
              acc[qr * 4 + i][qc * 2 + j] = __builtin_amdgcn_mfma_f32_16x16x32_bf16(
                  afr[i][kk], bfr[qc * 2 + j][kk], acc[qr * 4 + i][qc * 2 + j], 0, 0, 0);
        __builtin_amdgcn_s_setprio(0);
        if (q == 3) {  // staged slot must be visible next half
          asm volatile("s_waitcnt vmcnt(0)" ::: "memory");
          __builtin_amdgcn_s_barrier();
        }
      }
    }
  }

  const int rowl = g * 4;
#pragma unroll
  for (int bj = 0; bj < 4; ++bj) {
    const int gcol = n0 + wn * 64 + bj * 16 + lr;
    const float bv = bias[gcol];
#pragma unroll
    for (int ai = 0; ai < 8; ++ai) {
#pragma unroll
      for (int r = 0; r < 4; ++r) {
        int grow = m0 + wm * 128 + ai * 16 + rowl + r;
        float v = acc[ai][bj][r] + bv;
        if (OUT_MODE == 1) {
          ((float*)Cptr)[(size_t)grow * Dc + gcol] = v;
        } else if (OUT_MODE == 0) {
          ((short*)Cptr)[(size_t)grow * Dc + gcol] = f2bf(v);
        } else {
          int b4 = grow >> 11, ss = grow & (Sc - 1);
          int hh = gcol >> 7, dh = gcol & (DHc - 1);
          ((short*)Cptr)[((((size_t)(b4 * Hc + hh) * DHc) + dh) << 11) + ss] = f2bf(v);
        }
      }
    }
  }
}

// ---------------- flash attention (causal), QB=128 (32 q-rows/wave) --------
// Swapped QK^T (lane owns q-rows) + T14 async reg-staging, single-buffer.
// qp,kp: bf16 [B,S,D]; vt: bf16 [B,H,DH,S]; attn out: bf16 [B,S,D]
// LDS XOR-swizzled 16B slots: Ks[row][s^=(row&7)], Vs[d][s^=(d&7)].
__global__ __launch_bounds__(256, 2) void attn_kernel(
    const short* __restrict__ qp, const short* __restrict__ kp,
    const short* __restrict__ vt, short* __restrict__ attn) {
  __shared__ __align__(16) short Ks[64 * 128];
  __shared__ __align__(16) short Vs[128 * 64];
  __shared__ __align__(16) short Ps[4][32][72];
  const int tid = threadIdx.x, lane = tid & 63, wid = tid >> 6;
  const int lr = lane & 15, g = lane >> 4, lk = g * 8, rowl = g * 4;
  const int qb = ((int)gridDim.x - 1 - (int)blockIdx.x) * 128;  // longest first
  const int h = blockIdx.y, b = blockIdx.z;
  const size_t headq = ((size_t)b * Sc) * Dc + (size_t)h * DHc;
  const size_t vbase = (((size_t)b * Hc + h) * DHc) << 11;
  const int qw = qb + wid * 32;  // this wave's first q-row
  const int x7 = lr & 7;

  // Q fragments (B operand: col=lane&15=q-local, k contiguous)
  short8 qf[2][4];
#pragma unroll
  for (int qs = 0; qs < 2; ++qs)
#pragma unroll
    for (int c = 0; c < 4; ++c)
      qf[qs][c] = *(const short8*)&qp[headq + (size_t)(qw + qs * 16 + lr) * Dc + c * 32 + lk];

  // staging geometry
  const int krow = wid * 4 + g;
  const int kcol = lr * 8;
  const int vrow = wid * 8 + (lane >> 3);
  const int vcol = (lane & 7) * 8;
  int kdst[4], vdst[4];
#pragma unroll
  for (int p = 0; p < 4; ++p) {
    kdst[p] = (p * 16 + krow) * 128 + ((lr ^ (krow & 7)) * 8);
    vdst[p] = (p * 32 + vrow) * 64 + (((lane & 7) ^ (vrow & 7)) * 8);
  }

  short8 kreg[4], vreg[4];
  auto issue = [&](int kvb) {
#pragma unroll
    for (int p = 0; p < 4; ++p)
      kreg[p] = *(const short8*)&kp[headq + (size_t)(kvb + p * 16 + krow) * Dc + kcol];
#pragma unroll
    for (int p = 0; p < 4; ++p)
      vreg[p] = *(const short8*)&vt[vbase + (size_t)(p * 32 + vrow) * Sc + kvb + vcol];
  };
  auto commit = [&]() {
#pragma unroll
    for (int p = 0; p < 4; ++p) *(short8*)&Ks[kdst[p]] = kreg[p];
#pragma unroll
    for (int p = 0; p < 4; ++p) *(short8*)&Vs[vdst[p]] = vreg[p];
  };

  issue(0);
  commit();
  __syncthreads();

  f32x4 o[2][8] = {};
  float mrun[2] = {-1e30f, -1e30f}, lrun[2] = {0.f, 0.f};
  const int ntiles = qb / 64 + 2;

  for (int t = 0; t < ntiles; ++t) {
    const bool active = (64 * t <= qw + 31);  // wave-uniform
    f32x4 sc[2][4];

    if (active) {
      __builtin_amdgcn_s_setprio(1);
#pragma unroll
      for (int nb = 0; nb < 4; ++nb) {
        f32x4 s0 = {}, s1 = {};
#pragma unroll
        for (int c = 0; c < 4; ++c) {
          short8 kf = *(const short8*)&Ks[(nb * 16 + lr) * 128 + (((c * 4 + g) ^ x7) << 3)];
          s0 = __builtin_amdgcn_mfma_f32_16x16x32_bf16(kf, qf[0][c], s0, 0, 0, 0);
          s1 = __builtin_amdgcn_mfma_f32_16x16x32_bf16(kf, qf[1][c], s1, 0, 0, 0);
        }
        sc[0][nb] = s0;
        sc[1][nb] = s1;
      }
      __builtin_amdgcn_s_setprio(0);
    }

    if (t + 1 < ntiles) issue((t + 1) * 64);  // prefetch hides under softmax+PV

    if (active) {
      const bool domask = (64 * t + 63 > qw);
#pragma unroll
      for (int qs = 0; qs < 2; ++qs) {
        const int qg = qw + qs * 16 + lr;
        float mnb[4];
#pragma unroll
        for (int nb = 0; nb < 4; ++nb) {
#pragma unroll
          for (int r = 0; r < 4; ++r) {
            float v = sc[qs][nb][r] * SCALE;
            if (domask) {
              int kv = t * 64 + nb * 16 + rowl + r;
              v = (kv > qg) ? -1e30f : v;
            }
            sc[qs][nb][r] = v;
          }
          mnb[nb] = fmaxf(fmaxf(sc[qs][nb][0], sc[qs][nb][1]),
                          fmaxf(sc[qs][nb][2], sc[qs][nb][3]));
        }
        float mt = fmaxf(fmaxf(mnb[0], mnb[1]), fmaxf(mnb[2], mnb[3]));
        mt = fmaxf(mt, __shfl_xor(mt, 16));
        mt = fmaxf(mt, __shfl_xor(mt, 32));

        float mnew = fmaxf(mrun[qs], mt);
        float alpha = __expf(mrun[qs] - mnew);
        mrun[qs] = mnew;

        float lsnb[4];
#pragma unroll
        for (int nb = 0; nb < 4; ++nb) {
          float p0 = __expf(sc[qs][nb][0] - mnew);
          float p1 = __expf(sc[qs][nb][1] - mnew);
          float p2 = __expf(sc[qs][nb][2] - mnew);
          float p3 = __expf(sc[qs][nb][3] - mnew);
          lsnb[nb] = (p0 + p1) + (p2 + p3);
          uint2 w;
          w.x = pack2(p0, p1);
          w.y = pack2(p2, p3);
          *(uint2*)&Ps[wid][qs * 16 + lr][nb * 16 + rowl] = w;
        }
        float ls = (lsnb[0] + lsnb[1]) + (lsnb[2] + lsnb[3]);
        ls += __shfl_xor(ls, 16);
        ls += __shfl_xor(ls, 32);
        lrun[qs] = lrun[qs] * alpha + ls;

        float al[4];
#pragma unroll
        for (int r = 0; r < 4; ++r) al[r] = __shfl(alpha, (lane & 48) | (rowl + r));
#pragma unroll
        for (int f = 0; f < 8; ++f)
#pragma unroll
          for (int r = 0; r < 4; ++r) o[qs][f][r] *= al[r];
      }

      asm volatile("s_waitcnt lgkmcnt(0)" ::: "memory");
      __builtin_amdgcn_sched_barrier(0);

      __builtin_amdgcn_s_setprio(1);
#pragma unroll
      for (int kc = 0; kc < 2; ++kc) {
        short8 pf0 = *(const short8*)&Ps[wid][lr][kc * 32 + lk];
        short8 pf1 = *(const short8*)&Ps[wid][16 + lr][kc * 32 + lk];
#pragma unroll
        for (int nb = 0; nb < 8; ++nb) {
          short8 vf = *(const short8*)&Vs[(nb * 16 + lr) * 64 + (((kc * 4 + g) ^ x7) << 3)];
          o[0][nb] = __builtin_amdgcn_mfma_f32_16x16x32_bf16(pf0, vf, o[0][nb], 0, 0, 0);
          o[1][nb] = __builtin_amdgcn_mfma_f32_16x16x32_bf16(pf1, vf, o[1][nb], 0, 0, 0);
        }
      }
      __builtin_amdgcn_s_setprio(0);
    }

    __syncthreads();               // all Ks/Vs reads of tile t done
    if (t + 1 < ntiles) commit();  // vmcnt auto-wait + ds_write
    __syncthreads();               // tile t+1 visible
  }

#pragma unroll
  for (int qs = 0; qs < 2; ++qs) {
    float ld[4];
#pragma unroll
    for (int r = 0; r < 4; ++r) ld[r] = __shfl(lrun[qs], (lane & 48) | (rowl + r));
#pragma unroll
    for (int f = 0; f < 8; ++f)
#pragma unroll
      for (int r = 0; r < 4; ++r) {
        float v = o[qs][f][r] / ld[r];
        attn[headq + (size_t)(qw + qs * 16 + rowl + r) * Dc + f * 16 + lr] = f2bf(v);
      }
  }
}

// ---------------------------------------------------------------------------
extern "C" void kernel_launch(void* const* d_in, const int* in_sizes, int n_in,
                              void* d_out, int out_size, void* d_ws, size_t ws_size,
                              hipStream_t stream) {
  const float* Q = (const float*)d_in[0];
  const float* K = (const float*)d_in[1];
  const float* V = (const float*)d_in[2];
  // d_in[3] = mask (causal tril, structural — unused)
  const float* wq = (const float*)d_in[4];
  const float* bq = (const float*)d_in[5];
  const float* wk = (const float*)d_in[6];
  const float* bk = (const float*)d_in[7];
  const float* wv = (const float*)d_in[8];
  const float* bv = (const float*)d_in[9];
  const float* wo = (const float*)d_in[10];
  const float* bo = (const float*)d_in[11];

  char* ws = (char*)d_ws;
  const size_t WSZ = (size_t)Dc * Dc;
  const size_t XSZ = (size_t)Bc * Sc * Dc;
  short* WT = (short*)ws;
  short* QP = (short*)(ws + 4 * WSZ * 2);
  short* KP = (short*)(ws + 4 * WSZ * 2 + XSZ * 2);
  short* VT = (short*)(ws + 4 * WSZ * 2 + 2 * XSZ * 2);
  short* AT = (short*)(ws + 4 * WSZ * 2 + 3 * XSZ * 2);  // scratch: conv in, attn out
  // total: 8*WSZ + 8*XSZ bytes = 32 MiB + 128 MiB = 160 MiB

  transpose_w_kernel<<<dim3(Dc / 32, Dc / 32, 4), 256, 0, stream>>>(wq, wk, wv, wo, WT);

  const int n8 = (int)(XSZ / 8);
  const int ng = (Bc * Sc / 256) * (Dc / 256);  // 32*8 = 256 blocks

  convert_kernel<<<2048, 256, 0, stream>>>(Q, AT, n8);
  gemm256_kernel<0><<<ng, 512, 0, stream>>>(AT, WT, bq, QP);
  convert_kernel<<<2048, 256, 0, stream>>>(K, AT, n8);
  gemm256_kernel<0><<<ng, 512, 0, stream>>>(AT, WT + WSZ, bk, KP);
  convert_kernel<<<2048, 256, 0, stream>>>(V, AT, n8);
  gemm256_kernel<2><<<ng, 512, 0, stream>>>(AT, WT + 2 * WSZ, bv, VT);

  attn_kernel<<<dim3(Sc / 128, Hc, Bc), 256, 0, stream>>>(QP, KP, VT, AT);

  gemm256_kernel<1><<<ng, 512, 0, stream>>>(AT, WT + 3 * WSZ, bo, (float*)d_out);
}

// Round 6
// 524.036 us; speedup vs baseline: 1.7539x; 1.1540x over previous
//
#include <hip/hip_runtime.h>
#include <hip/hip_bf16.h>

typedef __attribute__((ext_vector_type(8))) short short8;
typedef __attribute__((ext_vector_type(4))) float f32x4;

#define DEVINL __device__ __forceinline__

constexpr int Bc = 4, Sc = 2048, Dc = 2048, Hc = 16, DHc = 128;
constexpr float SCALE = 0.08838834764831845f;  // 1/sqrt(128)

DEVINL short f2bf(float f) {
  unsigned u = __builtin_bit_cast(unsigned, f);
  u = (u + 0x7fffu + ((u >> 16) & 1u)) >> 16;
  return (short)u;
}
DEVINL unsigned pack2(float a, float b) {
  return (unsigned)(unsigned short)f2bf(a) | ((unsigned)(unsigned short)f2bf(b) << 16);
}

// async global->LDS, 16B per lane; LDS dest = wave-uniform base + lane*16
DEVINL void gload16(const void* g, void* l) {
  __builtin_amdgcn_global_load_lds(
      (const __attribute__((address_space(1))) void*)g,
      (__attribute__((address_space(3))) void*)l, 16, 0, 0);
}

// ---------------- weight transpose + fp32->bf16:  wt[n][k] = w[k][n] -------
__global__ __launch_bounds__(256) void transpose_w_kernel(
    const float* __restrict__ w0, const float* __restrict__ w1,
    const float* __restrict__ w2, const float* __restrict__ w3,
    short* __restrict__ wt) {
  __shared__ float tile[32][33];
  const float* w = (blockIdx.z == 0) ? w0 : (blockIdx.z == 1) ? w1
                   : (blockIdx.z == 2) ? w2 : w3;
  short* out = wt + (size_t)blockIdx.z * Dc * Dc;
  int k0 = blockIdx.x * 32, n0 = blockIdx.y * 32;
  int t = threadIdx.x;
#pragma unroll
  for (int p = 0; p < 4; ++p) {
    int idx = p * 256 + t;
    int kr = idx >> 5, nc = idx & 31;
    tile[kr][nc] = w[(size_t)(k0 + kr) * Dc + n0 + nc];
  }
  __syncthreads();
#pragma unroll
  for (int p = 0; p < 4; ++p) {
    int idx = p * 256 + t;
    int nr = idx >> 5, kc = idx & 31;
    out[(size_t)(n0 + nr) * Dc + k0 + kc] = f2bf(tile[kc][nr]);
  }
}

// ---------------- f32 -> bf16 convert (vectorized, grid-stride) ------------
__global__ __launch_bounds__(256) void convert_kernel(
    const float* __restrict__ in, short* __restrict__ out, int n8) {
  int stride = gridDim.x * 256;
  for (int idx = blockIdx.x * 256 + threadIdx.x; idx < n8; idx += stride) {
    const f32x4* p = (const f32x4*)(in + (size_t)idx * 8);
    f32x4 a = p[0], b = p[1];
    short8 r;
    r[0] = f2bf(a[0]); r[1] = f2bf(a[1]); r[2] = f2bf(a[2]); r[3] = f2bf(a[3]);
    r[4] = f2bf(b[0]); r[5] = f2bf(b[1]); r[6] = f2bf(b[2]); r[7] = f2bf(b[3]);
    *(short8*)(out + (size_t)idx * 8) = r;
  }
}

// ---------------- 256x256 8-phase GEMM: C = A[M,K] @ Wt[N,K]^T + bias ------
// 8 waves (2M x 4N), BK=64, LDS = 2 K-tile slots per tensor (128 KiB).
// OUT_MODE: 0 = bf16 [M,N], 1 = f32 [M,N], 2 = bf16 V-transposed [B,H,DH,S]
template <int OUT_MODE>
__global__ __launch_bounds__(512, 2) void gemm256_kernel(
    const short* __restrict__ A, const short* __restrict__ Wt,
    const float* __restrict__ bias, void* __restrict__ Cptr) {
  __shared__ __align__(16) short As[2][256 * 64];
  __shared__ __align__(16) short Bs[2][256 * 64];
  const int tid = threadIdx.x, lane = tid & 63, wid = tid >> 6;
  const int wm = wid >> 2, wn = wid & 3;
  const int lr = lane & 15, g = lane >> 4, x7 = lr & 7;

  // XCD-aware bijective swizzle: 256 blocks, 8 XCDs, 32 per XCD
  const int bid = blockIdx.x;
  const int swz = (bid & 7) * 32 + (bid >> 3);
  const int m0 = (swz >> 3) * 256, n0 = (swz & 7) * 256;

  // staging geometry: wave w covers rows w*8..w*8+7 per 64-row group
  const int srow8 = lane >> 3;                 // 0..7
  const int scol = ((lane & 7) ^ srow8) * 8;   // pre-swizzled source col
  const int arow = m0 + wid * 8 + srow8;
  const int brow = n0 + wid * 8 + srow8;
  const int ldst = wid * 8 * 128;              // bytes

  auto stageKt = [&](int kt, int slot) {
    const int kof = kt * 64 + scol;
#pragma unroll
    for (int h = 0; h < 2; ++h)
#pragma unroll
      for (int p2 = 0; p2 < 2; ++p2) {
        const int roff = h * 128 + p2 * 64;
        gload16(&A[(size_t)(arow + roff) * Dc + kof],
                (char*)&As[slot][0] + roff * 128 + ldst);
        gload16(&Wt[(size_t)(brow + roff) * Dc + kof],
                (char*)&Bs[slot][0] + roff * 128 + ldst);
      }
  };

  f32x4 acc[8][4] = {};

  stageKt(0, 0);
  asm volatile("s_waitcnt vmcnt(0)" ::: "memory");
  __builtin_amdgcn_s_barrier();

  for (int t = 0; t < 16; ++t) {
#pragma unroll
    for (int half = 0; half < 2; ++half) {
      const short* Ab = &As[half][0];
      const short* Bb = &Bs[half][0];
      short8 afr[4][2], bfr[4][2];
#pragma unroll
      for (int q = 0; q < 4; ++q) {
        // ---- fragment ds_reads for this phase (reuse across quadrants)
        if (q == 0) {
#pragma unroll
          for (int i = 0; i < 4; ++i)
#pragma unroll
            for (int kk = 0; kk < 2; ++kk)
              afr[i][kk] = *(const short8*)&Ab[(wm * 128 + i * 16 + lr) * 64 +
                                               (((kk * 4 + g) ^ x7) * 8)];
#pragma unroll
          for (int j = 0; j < 2; ++j)
#pragma unroll
            for (int kk = 0; kk < 2; ++kk)
              bfr[j][kk] = *(const short8*)&Bb[(wn * 64 + j * 16 + lr) * 64 +
                                               (((kk * 4 + g) ^ x7) * 8)];
        } else if (q == 1) {
#pragma unroll
          for (int j = 2; j < 4; ++j)
#pragma unroll
            for (int kk = 0; kk < 2; ++kk)
              bfr[j][kk] = *(const short8*)&Bb[(wn * 64 + j * 16 + lr) * 64 +
                                               (((kk * 4 + g) ^ x7) * 8)];
        } else if (q == 2) {
#pragma unroll
          for (int i = 0; i < 4; ++i)
#pragma unroll
            for (int kk = 0; kk < 2; ++kk)
              afr[i][kk] = *(const short8*)&Ab[(wm * 128 + 64 + i * 16 + lr) * 64 +
                                               (((kk * 4 + g) ^ x7) * 8)];
        }
        // ---- staging issue (early in the slot's free window)
        if (q == 0) {
          if (half == 0) stageKt(2 * t + 1, 1);
          else if (t < 15) stageKt(2 * t + 2, 0);
        }
        __builtin_amdgcn_s_barrier();
        asm volatile("s_waitcnt lgkmcnt(0)" ::: "memory");
        __builtin_amdgcn_sched_barrier(0);
        // ---- 16 MFMA: one C-quadrant x K=64
        __builtin_amdgcn_s_setprio(1);
        const int qr = q >> 1, qc = q & 1;
#pragma unroll
        for (int i = 0; i < 4; ++i)
#pragma unroll
          for (int j = 0; j < 2; ++j)
#pragma unroll
            for (int kk = 0; kk < 2; ++kk)
              acc[qr * 4 + i][qc * 2 + j] = __builtin_amdgcn_mfma_f32_16x16x32_bf16(
                  afr[i][kk], bfr[qc * 2 + j][kk], acc[qr * 4 + i][qc * 2 + j], 0, 0, 0);
        __builtin_amdgcn_s_setprio(0);
        if (q == 3) {  // staged slot must be visible next half
          asm volatile("s_waitcnt vmcnt(0)" ::: "memory");
          __builtin_amdgcn_s_barrier();
        }
      }
    }
  }

  const int rowl = g * 4;
#pragma unroll
  for (int bj = 0; bj < 4; ++bj) {
    const int gcol = n0 + wn * 64 + bj * 16 + lr;
    const float bv = bias[gcol];
#pragma unroll
    for (int ai = 0; ai < 8; ++ai) {
#pragma unroll
      for (int r = 0; r < 4; ++r) {
        int grow = m0 + wm * 128 + ai * 16 + rowl + r;
        float v = acc[ai][bj][r] + bv;
        if (OUT_MODE == 1) {
          ((float*)Cptr)[(size_t)grow * Dc + gcol] = v;
        } else if (OUT_MODE == 0) {
          ((short*)Cptr)[(size_t)grow * Dc + gcol] = f2bf(v);
        } else {
          int b4 = grow >> 11, ss = grow & (Sc - 1);
          int hh = gcol >> 7, dh = gcol & (DHc - 1);
          ((short*)Cptr)[((((size_t)(b4 * Hc + hh) * DHc) + dh) << 11) + ss] = f2bf(v);
        }
      }
    }
  }
}

// ---------------- flash attention (causal), QB=256, 8 waves ----------------
// Swapped QK^T (lane owns q-rows) + T14 async reg-staging, single-buffer.
// qp,kp: bf16 [B,S,D]; vt: bf16 [B,H,DH,S]; attn out: bf16 [B,S,D]
// LDS XOR-swizzled 16B slots: Ks[row][s^=(row&7)], Vs[d][s^=(d&7)].
// Grid 512 = 8 XCD * 8 heads * 8 qblocks: all q-blocks of a head stay on one
// XCD (K/V L2 locality); qi order 0,1,2,3,7,6,5,4 pairs long+short rounds.
__global__ __launch_bounds__(512, 2) void attn_kernel(
    const short* __restrict__ qp, const short* __restrict__ kp,
    const short* __restrict__ vt, short* __restrict__ attn) {
  __shared__ __align__(16) short Ks[64 * 128];
  __shared__ __align__(16) short Vs[128 * 64];
  __shared__ __align__(16) short Ps[8][32][72];
  const int tid = threadIdx.x, lane = tid & 63, wid = tid >> 6;
  const int lr = lane & 15, g = lane >> 4, lk = g * 8, rowl = g * 4;
  // block decode: XCD-clustered heads, duration-balanced qi order
  const int d = blockIdx.x;
  const int xcd = d & 7, s = d >> 3;
  const int grp = s >> 3;
  const int qi = (grp < 4) ? grp : 11 - grp;  // 0,1,2,3,7,6,5,4
  const int bh = xcd * 8 + (s & 7);
  const int b = bh >> 4, h = bh & 15;
  const int qb = qi * 256;
  const size_t headq = ((size_t)b * Sc) * Dc + (size_t)h * DHc;
  const size_t vbase = (((size_t)b * Hc + h) * DHc) << 11;
  const int qw = qb + wid * 32;  // this wave's first q-row
  const int x7 = lr & 7;

  // Q fragments (B operand: col=lane&15=q-local, k contiguous)
  short8 qf[2][4];
#pragma unroll
  for (int qs = 0; qs < 2; ++qs)
#pragma unroll
    for (int c = 0; c < 4; ++c)
      qf[qs][c] = *(const short8*)&qp[headq + (size_t)(qw + qs * 16 + lr) * Dc + c * 32 + lk];

  // staging geometry: K = 2 rounds x 32 rows, V = 2 rounds x 64 rows
  const int krow = wid * 4 + g;             // K row within 32-row group
  const int kcol = lr * 8;                  // linear source col (shorts)
  const int vrow = wid * 8 + (lane >> 3);   // V row within 64-row group
  const int vcol = (lane & 7) * 8;
  int kdst[2], vdst[2];
#pragma unroll
  for (int p = 0; p < 2; ++p) {
    int kr = p * 32 + krow;
    kdst[p] = kr * 128 + ((lr ^ (kr & 7)) * 8);
    int vr = p * 64 + vrow;
    vdst[p] = vr * 64 + (((lane & 7) ^ (vr & 7)) * 8);
  }

  short8 kreg[2], vreg[2];
  auto issue = [&](int kvb) {
#pragma unroll
    for (int p = 0; p < 2; ++p)
      kreg[p] = *(const short8*)&kp[headq + (size_t)(kvb + p * 32 + krow) * Dc + kcol];
#pragma unroll
    for (int p = 0; p < 2; ++p)
      vreg[p] = *(const short8*)&vt[vbase + (size_t)(p * 64 + vrow) * Sc + kvb + vcol];
  };
  auto commit = [&]() {
#pragma unroll
    for (int p = 0; p < 2; ++p) *(short8*)&Ks[kdst[p]] = kreg[p];
#pragma unroll
    for (int p = 0; p < 2; ++p) *(short8*)&Vs[vdst[p]] = vreg[p];
  };

  issue(0);
  commit();
  __syncthreads();

  f32x4 o[2][8] = {};
  float mrun[2] = {-1e30f, -1e30f}, lrun[2] = {0.f, 0.f};
  const int ntiles = qb / 64 + 4;

  for (int t = 0; t < ntiles; ++t) {
    const bool active = (64 * t <= qw + 31);  // wave-uniform
    f32x4 sc[2][4];

    if (active) {
      __builtin_amdgcn_s_setprio(1);
#pragma unroll
      for (int nb = 0; nb < 4; ++nb) {
        f32x4 s0 = {}, s1 = {};
#pragma unroll
        for (int c = 0; c < 4; ++c) {
          short8 kf = *(const short8*)&Ks[(nb * 16 + lr) * 128 + (((c * 4 + g) ^ x7) << 3)];
          s0 = __builtin_amdgcn_mfma_f32_16x16x32_bf16(kf, qf[0][c], s0, 0, 0, 0);
          s1 = __builtin_amdgcn_mfma_f32_16x16x32_bf16(kf, qf[1][c], s1, 0, 0, 0);
        }
        sc[0][nb] = s0;
        sc[1][nb] = s1;
      }
      __builtin_amdgcn_s_setprio(0);
    }

    if (t + 1 < ntiles) issue((t + 1) * 64);  // prefetch hides under softmax+PV

    if (active) {
      const bool domask = (64 * t + 63 > qw);
#pragma unroll
      for (int qs = 0; qs < 2; ++qs) {
        const int qg = qw + qs * 16 + lr;
        float mnb[4];
#pragma unroll
        for (int nb = 0; nb < 4; ++nb) {
#pragma unroll
          for (int r = 0; r < 4; ++r) {
            float v = sc[qs][nb][r] * SCALE;
            if (domask) {
              int kv = t * 64 + nb * 16 + rowl + r;
              v = (kv > qg) ? -1e30f : v;
            }
            sc[qs][nb][r] = v;
          }
          mnb[nb] = fmaxf(fmaxf(sc[qs][nb][0], sc[qs][nb][1]),
                          fmaxf(sc[qs][nb][2], sc[qs][nb][3]));
        }
        float mt = fmaxf(fmaxf(mnb[0], mnb[1]), fmaxf(mnb[2], mnb[3]));
        mt = fmaxf(mt, __shfl_xor(mt, 16));
        mt = fmaxf(mt, __shfl_xor(mt, 32));

        float mnew = fmaxf(mrun[qs], mt);
        float alpha = __expf(mrun[qs] - mnew);
        mrun[qs] = mnew;

        float lsnb[4];
#pragma unroll
        for (int nb = 0; nb < 4; ++nb) {
          float p0 = __expf(sc[qs][nb][0] - mnew);
          float p1 = __expf(sc[qs][nb][1] - mnew);
          float p2 = __expf(sc[qs][nb][2] - mnew);
          float p3 = __expf(sc[qs][nb][3] - mnew);
          lsnb[nb] = (p0 + p1) + (p2 + p3);
          uint2 w;
          w.x = pack2(p0, p1);
          w.y = pack2(p2, p3);
          *(uint2*)&Ps[wid][qs * 16 + lr][nb * 16 + rowl] = w;
        }
        float ls = (lsnb[0] + lsnb[1]) + (lsnb[2] + lsnb[3]);
        ls += __shfl_xor(ls, 16);
        ls += __shfl_xor(ls, 32);
        lrun[qs] = lrun[qs] * alpha + ls;

        float al[4];
#pragma unroll
        for (int r = 0; r < 4; ++r) al[r] = __shfl(alpha, (lane & 48) | (rowl + r));
#pragma unroll
        for (int f = 0; f < 8; ++f)
#pragma unroll
          for (int r = 0; r < 4; ++r) o[qs][f][r] *= al[r];
      }

      asm volatile("s_waitcnt lgkmcnt(0)" ::: "memory");
      __builtin_amdgcn_sched_barrier(0);

      __builtin_amdgcn_s_setprio(1);
#pragma unroll
      for (int kc = 0; kc < 2; ++kc) {
        short8 pf0 = *(const short8*)&Ps[wid][lr][kc * 32 + lk];
        short8 pf1 = *(const short8*)&Ps[wid][16 + lr][kc * 32 + lk];
#pragma unroll
        for (int nb = 0; nb < 8; ++nb) {
          short8 vf = *(const short8*)&Vs[(nb * 16 + lr) * 64 + (((kc * 4 + g) ^ x7) << 3)];
          o[0][nb] = __builtin_amdgcn_mfma_f32_16x16x32_bf16(pf0, vf, o[0][nb], 0, 0, 0);
          o[1][nb] = __builtin_amdgcn_mfma_f32_16x16x32_bf16(pf1, vf, o[1][nb], 0, 0, 0);
        }
      }
      __builtin_amdgcn_s_setprio(0);
    }

    __syncthreads();               // all Ks/Vs reads of tile t done
    if (t + 1 < ntiles) commit();  // vmcnt auto-wait + ds_write
    __syncthreads();               // tile t+1 visible
  }

#pragma unroll
  for (int qs = 0; qs < 2; ++qs) {
    float ld[4];
#pragma unroll
    for (int r = 0; r < 4; ++r) ld[r] = __shfl(lrun[qs], (lane & 48) | (rowl + r));
#pragma unroll
    for (int f = 0; f < 8; ++f)
#pragma unroll
      for (int r = 0; r < 4; ++r) {
        float v = o[qs][f][r] / ld[r];
        attn[headq + (size_t)(qw + qs * 16 + rowl + r) * Dc + f * 16 + lr] = f2bf(v);
      }
  }
}

// ---------------------------------------------------------------------------
extern "C" void kernel_launch(void* const* d_in, const int* in_sizes, int n_in,
                              void* d_out, int out_size, void* d_ws, size_t ws_size,
                              hipStream_t stream) {
  const float* Q = (const float*)d_in[0];
  const float* K = (const float*)d_in[1];
  const float* V = (const float*)d_in[2];
  // d_in[3] = mask (causal tril, structural — unused)
  const float* wq = (const float*)d_in[4];
  const float* bq = (const float*)d_in[5];
  const float* wk = (const float*)d_in[6];
  const float* bk = (const float*)d_in[7];
  const float* wv = (const float*)d_in[8];
  const float* bv = (const float*)d_in[9];
  const float* wo = (const float*)d_in[10];
  const float* bo = (const float*)d_in[11];

  char* ws = (char*)d_ws;
  const size_t WSZ = (size_t)Dc * Dc;
  const size_t XSZ = (size_t)Bc * Sc * Dc;
  short* WT = (short*)ws;
  short* QP = (short*)(ws + 4 * WSZ * 2);
  short* KP = (short*)(ws + 4 * WSZ * 2 + XSZ * 2);
  short* VT = (short*)(ws + 4 * WSZ * 2 + 2 * XSZ * 2);
  short* AT = (short*)(ws + 4 * WSZ * 2 + 3 * XSZ * 2);  // scratch: conv in, attn out
  // total: 8*WSZ + 8*XSZ bytes = 32 MiB + 128 MiB = 160 MiB

  transpose_w_kernel<<<dim3(Dc / 32, Dc / 32, 4), 256, 0, stream>>>(wq, wk, wv, wo, WT);

  const int n8 = (int)(XSZ / 8);
  const int ng = (Bc * Sc / 256) * (Dc / 256);  // 32*8 = 256 blocks

  convert_kernel<<<2048, 256, 0, stream>>>(Q, AT, n8);
  gemm256_kernel<0><<<ng, 512, 0, stream>>>(AT, WT, bq, QP);
  convert_kernel<<<2048, 256, 0, stream>>>(K, AT, n8);
  gemm256_kernel<0><<<ng, 512, 0, stream>>>(AT, WT + WSZ, bk, KP);
  convert_kernel<<<2048, 256, 0, stream>>>(V, AT, n8);
  gemm256_kernel<2><<<ng, 512, 0, stream>>>(AT, WT + 2 * WSZ, bv, VT);

  attn_kernel<<<512, 512, 0, stream>>>(QP, KP, VT, AT);

  gemm256_kernel<1><<<ng, 512, 0, stream>>>(AT, WT + 3 * WSZ, bo, (float*)d_out);
}

// Round 7
// 499.560 us; speedup vs baseline: 1.8398x; 1.0490x over previous
//
#include <hip/hip_runtime.h>
#include <hip/hip_bf16.h>

typedef __attribute__((ext_vector_type(8))) short short8;
typedef __attribute__((ext_vector_type(4))) float f32x4;

#define DEVINL __device__ __forceinline__

constexpr int Bc = 4, Sc = 2048, Dc = 2048, Hc = 16, DHc = 128;
constexpr float SCALE = 0.08838834764831845f;  // 1/sqrt(128)

DEVINL short f2bf(float f) {
  unsigned u = __builtin_bit_cast(unsigned, f);
  u = (u + 0x7fffu + ((u >> 16) & 1u)) >> 16;
  return (short)u;
}
DEVINL unsigned pack2(float a, float b) {
  return (unsigned)(unsigned short)f2bf(a) | ((unsigned)(unsigned short)f2bf(b) << 16);
}

// async global->LDS, 16B per lane; LDS dest = wave-uniform base + lane*16
DEVINL void gload16(const void* g, void* l) {
  __builtin_amdgcn_global_load_lds(
      (const __attribute__((address_space(1))) void*)g,
      (__attribute__((address_space(3))) void*)l, 16, 0, 0);
}

// ---------------- weight transpose + fp32->bf16:  wt[n][k] = w[k][n] -------
__global__ __launch_bounds__(256) void transpose_w_kernel(
    const float* __restrict__ w0, const float* __restrict__ w1,
    const float* __restrict__ w2, const float* __restrict__ w3,
    short* __restrict__ wt) {
  __shared__ float tile[32][33];
  const float* w = (blockIdx.z == 0) ? w0 : (blockIdx.z == 1) ? w1
                   : (blockIdx.z == 2) ? w2 : w3;
  short* out = wt + (size_t)blockIdx.z * Dc * Dc;
  int k0 = blockIdx.x * 32, n0 = blockIdx.y * 32;
  int t = threadIdx.x;
#pragma unroll
  for (int p = 0; p < 4; ++p) {
    int idx = p * 256 + t;
    int kr = idx >> 5, nc = idx & 31;
    tile[kr][nc] = w[(size_t)(k0 + kr) * Dc + n0 + nc];
  }
  __syncthreads();
#pragma unroll
  for (int p = 0; p < 4; ++p) {
    int idx = p * 256 + t;
    int nr = idx >> 5, kc = idx & 31;
    out[(size_t)(n0 + nr) * Dc + k0 + kc] = f2bf(tile[kc][nr]);
  }
}

// ---------------- f32 -> bf16 convert (vectorized, grid-stride) ------------
__global__ __launch_bounds__(256) void convert_kernel(
    const float* __restrict__ in, short* __restrict__ out, int n8) {
  int stride = gridDim.x * 256;
  for (int idx = blockIdx.x * 256 + threadIdx.x; idx < n8; idx += stride) {
    const f32x4* p = (const f32x4*)(in + (size_t)idx * 8);
    f32x4 a = p[0], b = p[1];
    short8 r;
    r[0] = f2bf(a[0]); r[1] = f2bf(a[1]); r[2] = f2bf(a[2]); r[3] = f2bf(a[3]);
    r[4] = f2bf(b[0]); r[5] = f2bf(b[1]); r[6] = f2bf(b[2]); r[7] = f2bf(b[3]);
    *(short8*)(out + (size_t)idx * 8) = r;
  }
}

// ---------------- 256x256 ring GEMM: C = A[M,K] @ Wt[N,K]^T + bias ---------
// 8 waves (2M x 4N), BK=32, 4-slot LDS ring (slot = kt&3, 128 KiB total).
// Per kt: 2 phases x {ds_read frags; issue 2 gloads (stage kt+3); barrier;
// lgkmcnt(0); 16 MFMA (setprio); barrier}. Counted vmcnt(8) once per kt:
// stage(kt+1) confirmed done while stage(kt+2)+stage(kt+3) (8 loads) stay in
// flight -> 5-6 phase prefetch distance, never drains to 0 (T4).
// LDS swizzle: 16B slot s at row r stored at s ^ ((r>>1)&3) -> 2-way (free).
// OUT_MODE: 0 = bf16 [M,N], 1 = f32 [M,N], 2 = bf16 V-transposed [B,H,DH,S]
template <int OUT_MODE>
__global__ __launch_bounds__(512, 2) void gemm_ring_kernel(
    const short* __restrict__ A, const short* __restrict__ Wt,
    const float* __restrict__ bias, void* __restrict__ Cptr) {
  __shared__ __align__(16) short As[4][256 * 32];
  __shared__ __align__(16) short Bs[4][256 * 32];
  const int tid = threadIdx.x, lane = tid & 63, wid = tid >> 6;
  const int wm = wid >> 2, wn = wid & 3;
  const int lr = lane & 15, g = lane >> 4;
  const int physg = (g ^ ((lr >> 1) & 3)) * 8;  // swizzled read col (shorts)

  // XCD-aware bijective swizzle: 256 blocks, 8 XCDs, 32 per XCD
  const int bid = blockIdx.x;
  const int swz = (bid & 7) * 32 + (bid >> 3);
  const int m0 = (swz >> 3) * 256, n0 = (swz & 7) * 256;

  // staging: wave stages rows wid*32..wid*32+31 (2 gloads per tensor per kt)
  const int srow = lane >> 2;                        // 0..15
  const int scol = ((lane & 3) ^ ((lane >> 3) & 3)) * 8;  // pre-swizzled src col
  const size_t abase = (size_t)(m0 + wid * 32 + srow) * Dc + scol;
  const size_t bbase = (size_t)(n0 + wid * 32 + srow) * Dc + scol;
  const int ldof = wid * 32 * 64;  // byte offset of wave's row block

  auto stageA = [&](int kt) {
    const short* src = &A[abase + kt * 32];
    char* dst = (char*)&As[kt & 3][0] + ldof;
    gload16(src, dst);
    gload16(src + (size_t)16 * Dc, dst + 16 * 64);
  };
  auto stageB = [&](int kt) {
    const short* src = &Wt[bbase + kt * 32];
    char* dst = (char*)&Bs[kt & 3][0] + ldof;
    gload16(src, dst);
    gload16(src + (size_t)16 * Dc, dst + 16 * 64);
  };

  f32x4 acc[8][4] = {};

  stageA(0); stageB(0);
  stageA(1); stageB(1);
  stageA(2); stageB(2);
  asm volatile("s_waitcnt vmcnt(8)" ::: "memory");  // stage(0) done
  __builtin_amdgcn_s_barrier();

  for (int kt = 0; kt < 64; ++kt) {
    const short* Ab = &As[kt & 3][0];
    const short* Bb = &Bs[kt & 3][0];
    short8 afr[4], bfr[4];

    // ---- phase 0: frags (A rows 0-63 of wave block + all B) + stage A(kt+3)
#pragma unroll
    for (int i = 0; i < 4; ++i)
      afr[i] = *(const short8*)&Ab[(wm * 128 + i * 16 + lr) * 32 + physg];
#pragma unroll
    for (int j = 0; j < 4; ++j)
      bfr[j] = *(const short8*)&Bb[(wn * 64 + j * 16 + lr) * 32 + physg];
    if (kt < 61) stageA(kt + 3);
    __builtin_amdgcn_s_barrier();
    asm volatile("s_waitcnt lgkmcnt(0)" ::: "memory");
    __builtin_amdgcn_sched_barrier(0);
    __builtin_amdgcn_s_setprio(1);
#pragma unroll
    for (int i = 0; i < 4; ++i)
#pragma unroll
      for (int j = 0; j < 4; ++j)
        acc[i][j] = __builtin_amdgcn_mfma_f32_16x16x32_bf16(afr[i], bfr[j], acc[i][j], 0, 0, 0);
    __builtin_amdgcn_s_setprio(0);
    __builtin_amdgcn_s_barrier();

    // ---- phase 1: frags (A rows 64-127 of wave block) + stage B(kt+3)
#pragma unroll
    for (int i = 0; i < 4; ++i)
      afr[i] = *(const short8*)&Ab[(wm * 128 + 64 + i * 16 + lr) * 32 + physg];
    if (kt < 61) stageB(kt + 3);
    __builtin_amdgcn_s_barrier();
    asm volatile("s_waitcnt lgkmcnt(0)" ::: "memory");
    __builtin_amdgcn_sched_barrier(0);
    __builtin_amdgcn_s_setprio(1);
#pragma unroll
    for (int i = 0; i < 4; ++i)
#pragma unroll
      for (int j = 0; j < 4; ++j)
        acc[4 + i][j] = __builtin_amdgcn_mfma_f32_16x16x32_bf16(afr[i], bfr[j], acc[4 + i][j], 0, 0, 0);
    __builtin_amdgcn_s_setprio(0);
    // counted wait: stage(kt+1) must be complete; keep 8 loads in flight
    if (kt <= 60) {
      asm volatile("s_waitcnt vmcnt(8)" ::: "memory");
    } else if (kt == 61) {
      asm volatile("s_waitcnt vmcnt(4)" ::: "memory");
    } else if (kt == 62) {
      asm volatile("s_waitcnt vmcnt(0)" ::: "memory");
    }
    __builtin_amdgcn_s_barrier();
  }

  const int rowl = g * 4;
#pragma unroll
  for (int bj = 0; bj < 4; ++bj) {
    const int gcol = n0 + wn * 64 + bj * 16 + lr;
    const float bv = bias[gcol];
#pragma unroll
    for (int ai = 0; ai < 8; ++ai) {
#pragma unroll
      for (int r = 0; r < 4; ++r) {
        int grow = m0 + wm * 128 + ai * 16 + rowl + r;
        float v = acc[ai][bj][r] + bv;
        if (OUT_MODE == 1) {
          ((float*)Cptr)[(size_t)grow * Dc + gcol] = v;
        } else if (OUT_MODE == 0) {
          ((short*)Cptr)[(size_t)grow * Dc + gcol] = f2bf(v);
        } else {
          int b4 = grow >> 11, ss = grow & (Sc - 1);
          int hh = gcol >> 7, dh = gcol & (DHc - 1);
          ((short*)Cptr)[((((size_t)(b4 * Hc + hh) * DHc) + dh) << 11) + ss] = f2bf(v);
        }
      }
    }
  }
}

// ---------------- flash attention (causal), QB=256, 8 waves ----------------
// Swapped QK^T (lane owns q-rows) + T14 async reg-staging, single-buffer.
// qp,kp: bf16 [B,S,D]; vt: bf16 [B,H,DH,S]; attn out: bf16 [B,S,D]
// LDS XOR-swizzled 16B slots: Ks[row][s^=(row&7)], Vs[d][s^=(d&7)].
// Grid 512 = 8 XCD * 8 heads * 8 qblocks: all q-blocks of a head stay on one
// XCD (K/V L2 locality); qi order 0,1,2,3,7,6,5,4 pairs long+short rounds.
__global__ __launch_bounds__(512, 2) void attn_kernel(
    const short* __restrict__ qp, const short* __restrict__ kp,
    const short* __restrict__ vt, short* __restrict__ attn) {
  __shared__ __align__(16) short Ks[64 * 128];
  __shared__ __align__(16) short Vs[128 * 64];
  __shared__ __align__(16) short Ps[8][32][72];
  const int tid = threadIdx.x, lane = tid & 63, wid = tid >> 6;
  const int lr = lane & 15, g = lane >> 4, lk = g * 8, rowl = g * 4;
  // block decode: XCD-clustered heads, duration-balanced qi order
  const int d = blockIdx.x;
  const int xcd = d & 7, s = d >> 3;
  const int grp = s >> 3;
  const int qi = (grp < 4) ? grp : 11 - grp;  // 0,1,2,3,7,6,5,4
  const int bh = xcd * 8 + (s & 7);
  const int b = bh >> 4, h = bh & 15;
  const int qb = qi * 256;
  const size_t headq = ((size_t)b * Sc) * Dc + (size_t)h * DHc;
  const size_t vbase = (((size_t)b * Hc + h) * DHc) << 11;
  const int qw = qb + wid * 32;  // this wave's first q-row
  const int x7 = lr & 7;

  // Q fragments (B operand: col=lane&15=q-local, k contiguous)
  short8 qf[2][4];
#pragma unroll
  for (int qs = 0; qs < 2; ++qs)
#pragma unroll
    for (int c = 0; c < 4; ++c)
      qf[qs][c] = *(const short8*)&qp[headq + (size_t)(qw + qs * 16 + lr) * Dc + c * 32 + lk];

  // staging geometry: K = 2 rounds x 32 rows, V = 2 rounds x 64 rows
  const int krow = wid * 4 + g;             // K row within 32-row group
  const int kcol = lr * 8;                  // linear source col (shorts)
  const int vrow = wid * 8 + (lane >> 3);   // V row within 64-row group
  const int vcol = (lane & 7) * 8;
  int kdst[2], vdst[2];
#pragma unroll
  for (int p = 0; p < 2; ++p) {
    int kr = p * 32 + krow;
    kdst[p] = kr * 128 + ((lr ^ (kr & 7)) * 8);
    int vr = p * 64 + vrow;
    vdst[p] = vr * 64 + (((lane & 7) ^ (vr & 7)) * 8);
  }

  short8 kreg[2], vreg[2];
  auto issue = [&](int kvb) {
#pragma unroll
    for (int p = 0; p < 2; ++p)
      kreg[p] = *(const short8*)&kp[headq + (size_t)(kvb + p * 32 + krow) * Dc + kcol];
#pragma unroll
    for (int p = 0; p < 2; ++p)
      vreg[p] = *(const short8*)&vt[vbase + (size_t)(p * 64 + vrow) * Sc + kvb + vcol];
  };
  auto commit = [&]() {
#pragma unroll
    for (int p = 0; p < 2; ++p) *(short8*)&Ks[kdst[p]] = kreg[p];
#pragma unroll
    for (int p = 0; p < 2; ++p) *(short8*)&Vs[vdst[p]] = vreg[p];
  };

  issue(0);
  commit();
  __syncthreads();

  f32x4 o[2][8] = {};
  float mrun[2] = {-1e30f, -1e30f}, lrun[2] = {0.f, 0.f};
  const int ntiles = qb / 64 + 4;

  for (int t = 0; t < ntiles; ++t) {
    const bool active = (64 * t <= qw + 31);  // wave-uniform
    f32x4 sc[2][4];

    if (active) {
      __builtin_amdgcn_s_setprio(1);
#pragma unroll
      for (int nb = 0; nb < 4; ++nb) {
        f32x4 s0 = {}, s1 = {};
#pragma unroll
        for (int c = 0; c < 4; ++c) {
          short8 kf = *(const short8*)&Ks[(nb * 16 + lr) * 128 + (((c * 4 + g) ^ x7) << 3)];
          s0 = __builtin_amdgcn_mfma_f32_16x16x32_bf16(kf, qf[0][c], s0, 0, 0, 0);
          s1 = __builtin_amdgcn_mfma_f32_16x16x32_bf16(kf, qf[1][c], s1, 0, 0, 0);
        }
        sc[0][nb] = s0;
        sc[1][nb] = s1;
      }
      __builtin_amdgcn_s_setprio(0);
    }

    if (t + 1 < ntiles) issue((t + 1) * 64);  // prefetch hides under softmax+PV

    if (active) {
      const bool domask = (64 * t + 63 > qw);
#pragma unroll
      for (int qs = 0; qs < 2; ++qs) {
        const int qg = qw + qs * 16 + lr;
        float mnb[4];
#pragma unroll
        for (int nb = 0; nb < 4; ++nb) {
#pragma unroll
          for (int r = 0; r < 4; ++r) {
            float v = sc[qs][nb][r] * SCALE;
            if (domask) {
              int kv = t * 64 + nb * 16 + rowl + r;
              v = (kv > qg) ? -1e30f : v;
            }
            sc[qs][nb][r] = v;
          }
          mnb[nb] = fmaxf(fmaxf(sc[qs][nb][0], sc[qs][nb][1]),
                          fmaxf(sc[qs][nb][2], sc[qs][nb][3]));
        }
        float mt = fmaxf(fmaxf(mnb[0], mnb[1]), fmaxf(mnb[2], mnb[3]));
        mt = fmaxf(mt, __shfl_xor(mt, 16));
        mt = fmaxf(mt, __shfl_xor(mt, 32));

        float mnew = fmaxf(mrun[qs], mt);
        float alpha = __expf(mrun[qs] - mnew);
        mrun[qs] = mnew;

        float lsnb[4];
#pragma unroll
        for (int nb = 0; nb < 4; ++nb) {
          float p0 = __expf(sc[qs][nb][0] - mnew);
          float p1 = __expf(sc[qs][nb][1] - mnew);
          float p2 = __expf(sc[qs][nb][2] - mnew);
          float p3 = __expf(sc[qs][nb][3] - mnew);
          lsnb[nb] = (p0 + p1) + (p2 + p3);
          uint2 w;
          w.x = pack2(p0, p1);
          w.y = pack2(p2, p3);
          *(uint2*)&Ps[wid][qs * 16 + lr][nb * 16 + rowl] = w;
        }
        float ls = (lsnb[0] + lsnb[1]) + (lsnb[2] + lsnb[3]);
        ls += __shfl_xor(ls, 16);
        ls += __shfl_xor(ls, 32);
        lrun[qs] = lrun[qs] * alpha + ls;

        float al[4];
#pragma unroll
        for (int r = 0; r < 4; ++r) al[r] = __shfl(alpha, (lane & 48) | (rowl + r));
#pragma unroll
        for (int f = 0; f < 8; ++f)
#pragma unroll
          for (int r = 0; r < 4; ++r) o[qs][f][r] *= al[r];
      }

      asm volatile("s_waitcnt lgkmcnt(0)" ::: "memory");
      __builtin_amdgcn_sched_barrier(0);

      __builtin_amdgcn_s_setprio(1);
#pragma unroll
      for (int kc = 0; kc < 2; ++kc) {
        short8 pf0 = *(const short8*)&Ps[wid][lr][kc * 32 + lk];
        short8 pf1 = *(const short8*)&Ps[wid][16 + lr][kc * 32 + lk];
#pragma unroll
        for (int nb = 0; nb < 8; ++nb) {
          short8 vf = *(const short8*)&Vs[(nb * 16 + lr) * 64 + (((kc * 4 + g) ^ x7) << 3)];
          o[0][nb] = __builtin_amdgcn_mfma_f32_16x16x32_bf16(pf0, vf, o[0][nb], 0, 0, 0);
          o[1][nb] = __builtin_amdgcn_mfma_f32_16x16x32_bf16(pf1, vf, o[1][nb], 0, 0, 0);
        }
      }
      __builtin_amdgcn_s_setprio(0);
    }

    __syncthreads();               // all Ks/Vs reads of tile t done
    if (t + 1 < ntiles) commit();  // vmcnt auto-wait + ds_write
    __syncthreads();               // tile t+1 visible
  }

#pragma unroll
  for (int qs = 0; qs < 2; ++qs) {
    float ld[4];
#pragma unroll
    for (int r = 0; r < 4; ++r) ld[r] = __shfl(lrun[qs], (lane & 48) | (rowl + r));
#pragma unroll
    for (int f = 0; f < 8; ++f)
#pragma unroll
      for (int r = 0; r < 4; ++r) {
        float v = o[qs][f][r] / ld[r];
        attn[headq + (size_t)(qw + qs * 16 + rowl + r) * Dc + f * 16 + lr] = f2bf(v);
      }
  }
}

// ---------------------------------------------------------------------------
extern "C" void kernel_launch(void* const* d_in, const int* in_sizes, int n_in,
                              void* d_out, int out_size, void* d_ws, size_t ws_size,
                              hipStream_t stream) {
  const float* Q = (const float*)d_in[0];
  const float* K = (const float*)d_in[1];
  const float* V = (const float*)d_in[2];
  // d_in[3] = mask (causal tril, structural — unused)
  const float* wq = (const float*)d_in[4];
  const float* bq = (const float*)d_in[5];
  const float* wk = (const float*)d_in[6];
  const float* bk = (const float*)d_in[7];
  const float* wv = (const float*)d_in[8];
  const float* bv = (const float*)d_in[9];
  const float* wo = (const float*)d_in[10];
  const float* bo = (const float*)d_in[11];

  char* ws = (char*)d_ws;
  const size_t WSZ = (size_t)Dc * Dc;
  const size_t XSZ = (size_t)Bc * Sc * Dc;
  short* WT = (short*)ws;
  short* QP = (short*)(ws + 4 * WSZ * 2);
  short* KP = (short*)(ws + 4 * WSZ * 2 + XSZ * 2);
  short* VT = (short*)(ws + 4 * WSZ * 2 + 2 * XSZ * 2);
  short* AT = (short*)(ws + 4 * WSZ * 2 + 3 * XSZ * 2);  // scratch: conv in, attn out
  // total: 8*WSZ + 8*XSZ bytes = 32 MiB + 128 MiB = 160 MiB

  transpose_w_kernel<<<dim3(Dc / 32, Dc / 32, 4), 256, 0, stream>>>(wq, wk, wv, wo, WT);

  const int n8 = (int)(XSZ / 8);
  const int ng = (Bc * Sc / 256) * (Dc / 256);  // 32*8 = 256 blocks

  convert_kernel<<<2048, 256, 0, stream>>>(Q, AT, n8);
  gemm_ring_kernel<0><<<ng, 512, 0, stream>>>(AT, WT, bq, QP);
  convert_kernel<<<2048, 256, 0, stream>>>(K, AT, n8);
  gemm_ring_kernel<0><<<ng, 512, 0, stream>>>(AT, WT + WSZ, bk, KP);
  convert_kernel<<<2048, 256, 0, stream>>>(V, AT, n8);
  gemm_ring_kernel<2><<<ng, 512, 0, stream>>>(AT, WT + 2 * WSZ, bv, VT);

  attn_kernel<<<512, 512, 0, stream>>>(QP, KP, VT, AT);

  gemm_ring_kernel<1><<<ng, 512, 0, stream>>>(AT, WT + 3 * WSZ, bo, (float*)d_out);
}

// Round 9
// 475.279 us; speedup vs baseline: 1.9338x; 1.0511x over previous
//
#include <hip/hip_runtime.h>
#include <hip/hip_bf16.h>

typedef __attribute__((ext_vector_type(8))) short short8;
typedef __attribute__((ext_vector_type(4))) float f32x4;

#define DEVINL __device__ __forceinline__

constexpr int Bc = 4, Sc = 2048, Dc = 2048, Hc = 16, DHc = 128;
// softmax in exp2 space: scores pre-scaled by 1/sqrt(128) * log2(e)
constexpr float SCALE2 = 0.08838834764831845f * 1.4426950408889634f;

DEVINL float exp2s(float x) { return __builtin_amdgcn_exp2f(x); }

DEVINL short f2bf(float f) {
  unsigned u = __builtin_bit_cast(unsigned, f);
  u = (u + 0x7fffu + ((u >> 16) & 1u)) >> 16;
  return (short)u;
}
DEVINL unsigned pack2(float a, float b) {
  return (unsigned)(unsigned short)f2bf(a) | ((unsigned)(unsigned short)f2bf(b) << 16);
}

// async global->LDS, 16B per lane; LDS dest = wave-uniform base + lane*16
DEVINL void gload16(const void* g, void* l) {
  __builtin_amdgcn_global_load_lds(
      (const __attribute__((address_space(1))) void*)g,
      (__attribute__((address_space(3))) void*)l, 16, 0, 0);
}

// ---------------- weight transpose + fp32->bf16:  wt[n][k] = w[k][n] -------
__global__ __launch_bounds__(256) void transpose_w_kernel(
    const float* __restrict__ w0, const float* __restrict__ w1,
    const float* __restrict__ w2, const float* __restrict__ w3,
    short* __restrict__ wt) {
  __shared__ float tile[32][33];
  const float* w = (blockIdx.z == 0) ? w0 : (blockIdx.z == 1) ? w1
                   : (blockIdx.z == 2) ? w2 : w3;
  short* out = wt + (size_t)blockIdx.z * Dc * Dc;
  int k0 = blockIdx.x * 32, n0 = blockIdx.y * 32;
  int t = threadIdx.x;
#pragma unroll
  for (int p = 0; p < 4; ++p) {
    int idx = p * 256 + t;
    int kr = idx >> 5, nc = idx & 31;
    tile[kr][nc] = w[(size_t)(k0 + kr) * Dc + n0 + nc];
  }
  __syncthreads();
#pragma unroll
  for (int p = 0; p < 4; ++p) {
    int idx = p * 256 + t;
    int nr = idx >> 5, kc = idx & 31;
    out[(size_t)(n0 + nr) * Dc + k0 + kc] = f2bf(tile[kc][nr]);
  }
}

// ---------------- f32 -> bf16 convert (vectorized, grid-stride) ------------
__global__ __launch_bounds__(256) void convert_kernel(
    const float* __restrict__ in, short* __restrict__ out, int n8) {
  int stride = gridDim.x * 256;
  for (int idx = blockIdx.x * 256 + threadIdx.x; idx < n8; idx += stride) {
    const f32x4* p = (const f32x4*)(in + (size_t)idx * 8);
    f32x4 a = p[0], b = p[1];
    short8 r;
    r[0] = f2bf(a[0]); r[1] = f2bf(a[1]); r[2] = f2bf(a[2]); r[3] = f2bf(a[3]);
    r[4] = f2bf(b[0]); r[5] = f2bf(b[1]); r[6] = f2bf(b[2]); r[7] = f2bf(b[3]);
    *(short8*)(out + (size_t)idx * 8) = r;
  }
}

// ---------------- 256x256 ring GEMM: C = A[M,K] @ Wt[N,K]^T + bias ---------
// 8 waves (2M x 4N), BK=32, 4-slot LDS ring (slot = kt&3, 128 KiB).
// ONE barrier + ONE counted vmcnt per kt (32 MFMA): slot kt&3 written only by
// stage(kt) -- vmcnt(8)-then-barrier proves all waves' loads landed; slot
// reuse is 4 kt away so no intra-kt sync. No lgkmcnt(0) lockstep: compiler
// emits fine-grained lgkm waits for ds_read->MFMA.
// __launch_bounds__(512,1): 1 block/CU (LDS-bound anyway) -> 256-VGPR budget
// (acc 128 + frags 48); the old (512,2) capped at 128 VGPR and spilled.
// LDS swizzle: 16B slot s at row r stored at s ^ ((r>>1)&3) -> balanced banks.
// OUT_MODE: 0 = bf16 [M,N], 1 = f32 [M,N], 2 = bf16 V-transposed [B,H,DH,S]
template <int OUT_MODE>
__global__ __launch_bounds__(512, 1) void gemm_ring_kernel(
    const short* __restrict__ A, const short* __restrict__ Wt,
    const float* __restrict__ bias, void* __restrict__ Cptr) {
  __shared__ __align__(16) short As[4][256 * 32];
  __shared__ __align__(16) short Bs[4][256 * 32];
  const int tid = threadIdx.x, lane = tid & 63, wid = tid >> 6;
  const int wm = wid >> 2, wn = wid & 3;
  const int lr = lane & 15, g = lane >> 4;
  const int physg = (g ^ ((lr >> 1) & 3)) * 8;  // swizzled read col (shorts)

  // XCD-aware bijective swizzle: 256 blocks, 8 XCDs, 32 per XCD
  const int bid = blockIdx.x;
  const int swz = (bid & 7) * 32 + (bid >> 3);
  const int m0 = (swz >> 3) * 256, n0 = (swz & 7) * 256;

  // staging: wave stages rows wid*32..wid*32+31 (2 gloads per tensor per kt)
  const int srow = lane >> 2;                             // 0..15
  const int scol = ((lane & 3) ^ ((lane >> 3) & 3)) * 8;  // pre-swizzled src col
  const size_t abase = (size_t)(m0 + wid * 32 + srow) * Dc + scol;
  const size_t bbase = (size_t)(n0 + wid * 32 + srow) * Dc + scol;
  const int ldof = wid * 32 * 64;  // byte offset of wave's row block

  auto stageA = [&](int kt) {
    const short* src = &A[abase + kt * 32];
    char* dst = (char*)&As[kt & 3][0] + ldof;
    gload16(src, dst);
    gload16(src + (size_t)16 * Dc, dst + 16 * 64);
  };
  auto stageB = [&](int kt) {
    const short* src = &Wt[bbase + kt * 32];
    char* dst = (char*)&Bs[kt & 3][0] + ldof;
    gload16(src, dst);
    gload16(src + (size_t)16 * Dc, dst + 16 * 64);
  };

  f32x4 acc[8][4] = {};

  stageA(0); stageB(0);
  stageA(1); stageB(1);
  stageA(2); stageB(2);

  for (int kt = 0; kt < 64; ++kt) {
    // counted wait: own stage(kt) done; barrier => ALL waves' stage(kt) done.
    // keeps stage(kt+1), stage(kt+2) [, stage(kt+3)] in flight across barrier.
    if (kt < 62) {
      asm volatile("s_waitcnt vmcnt(8)" ::: "memory");
    } else if (kt == 62) {
      asm volatile("s_waitcnt vmcnt(4)" ::: "memory");
    } else {
      asm volatile("s_waitcnt vmcnt(0)" ::: "memory");
    }
    __builtin_amdgcn_s_barrier();
    asm volatile("" ::: "memory");  // reads may not hoist above the barrier

    const short* Ab = &As[kt & 3][0];
    const short* Bb = &Bs[kt & 3][0];
    short8 afr[4], bfr[4], af2[4];
#pragma unroll
    for (int i = 0; i < 4; ++i)
      afr[i] = *(const short8*)&Ab[(wm * 128 + i * 16 + lr) * 32 + physg];
#pragma unroll
    for (int j = 0; j < 4; ++j)
      bfr[j] = *(const short8*)&Bb[(wn * 64 + j * 16 + lr) * 32 + physg];
#pragma unroll
    for (int i = 0; i < 4; ++i)
      af2[i] = *(const short8*)&Ab[(wm * 128 + 64 + i * 16 + lr) * 32 + physg];

    if (kt <= 60) { stageA(kt + 3); stageB(kt + 3); }  // writes slot (kt-1)&3

    __builtin_amdgcn_s_setprio(1);
#pragma unroll
    for (int i = 0; i < 4; ++i)
#pragma unroll
      for (int j = 0; j < 4; ++j)
        acc[i][j] = __builtin_amdgcn_mfma_f32_16x16x32_bf16(afr[i], bfr[j], acc[i][j], 0, 0, 0);
#pragma unroll
    for (int i = 0; i < 4; ++i)
#pragma unroll
      for (int j = 0; j < 4; ++j)
        acc[4 + i][j] = __builtin_amdgcn_mfma_f32_16x16x32_bf16(af2[i], bfr[j], acc[4 + i][j], 0, 0, 0);
    __builtin_amdgcn_s_setprio(0);
  }

  const int rowl = g * 4;
#pragma unroll
  for (int bj = 0; bj < 4; ++bj) {
    const int gcol = n0 + wn * 64 + bj * 16 + lr;
    const float bv = bias[gcol];
#pragma unroll
    for (int ai = 0; ai < 8; ++ai) {
#pragma unroll
      for (int r = 0; r < 4; ++r) {
        int grow = m0 + wm * 128 + ai * 16 + rowl + r;
        float v = acc[ai][bj][r] + bv;
        if (OUT_MODE == 1) {
          ((float*)Cptr)[(size_t)grow * Dc + gcol] = v;
        } else if (OUT_MODE == 0) {
          ((short*)Cptr)[(size_t)grow * Dc + gcol] = f2bf(v);
        } else {
          int b4 = grow >> 11, ss = grow & (Sc - 1);
          int hh = gcol >> 7, dh = gcol & (DHc - 1);
          ((short*)Cptr)[((((size_t)(b4 * Hc + hh) * DHc) + dh) << 11) + ss] = f2bf(v);
        }
      }
    }
  }
}

// ---------------- flash attention (causal), QB=256, 8 waves ----------------
// Swapped QK^T (lane owns q-rows) + T14 async reg-staging, single-buffer.
// Softmax in exp2 space (SCALE2 = scale*log2e). qp,kp: bf16 [B,S,D];
// vt: bf16 [B,H,DH,S]; attn out: bf16 [B,S,D].
// LDS XOR-swizzled 16B slots: Ks[row][s^=(row&7)], Vs[d][s^=(d&7)].
// Grid 512 = 8 XCD * 8 heads * 8 qblocks: all q-blocks of a head stay on one
// XCD (K/V L2 locality); qi order 0,1,2,3,7,6,5,4 pairs long+short rounds.
__global__ __launch_bounds__(512, 2) void attn_kernel(
    const short* __restrict__ qp, const short* __restrict__ kp,
    const short* __restrict__ vt, short* __restrict__ attn) {
  __shared__ __align__(16) short Ks[64 * 128];
  __shared__ __align__(16) short Vs[128 * 64];
  __shared__ __align__(16) short Ps[8][32][72];
  const int tid = threadIdx.x, lane = tid & 63, wid = tid >> 6;
  const int lr = lane & 15, g = lane >> 4, lk = g * 8, rowl = g * 4;
  // block decode: XCD-clustered heads, duration-balanced qi order
  const int d = blockIdx.x;
  const int xcd = d & 7, s = d >> 3;
  const int grp = s >> 3;
  const int qi = (grp < 4) ? grp : 11 - grp;  // 0,1,2,3,7,6,5,4
  const int bh = xcd * 8 + (s & 7);
  const int b = bh >> 4, h = bh & 15;
  const int qb = qi * 256;
  const size_t headq = ((size_t)b * Sc) * Dc + (size_t)h * DHc;
  const size_t vbase = (((size_t)b * Hc + h) * DHc) << 11;
  const int qw = qb + wid * 32;  // this wave's first q-row
  const int x7 = lr & 7;

  // Q fragments (B operand: col=lane&15=q-local, k contiguous)
  short8 qf[2][4];
#pragma unroll
  for (int qs = 0; qs < 2; ++qs)
#pragma unroll
    for (int c = 0; c < 4; ++c)
      qf[qs][c] = *(const short8*)&qp[headq + (size_t)(qw + qs * 16 + lr) * Dc + c * 32 + lk];

  // staging geometry: K = 2 rounds x 32 rows, V = 2 rounds x 64 rows
  const int krow = wid * 4 + g;             // K row within 32-row group
  const int kcol = lr * 8;                  // linear source col (shorts)
  const int vrow = wid * 8 + (lane >> 3);   // V row within 64-row group
  const int vcol = (lane & 7) * 8;
  int kdst[2], vdst[2];
#pragma unroll
  for (int p = 0; p < 2; ++p) {
    int kr = p * 32 + krow;
    kdst[p] = kr * 128 + ((lr ^ (kr & 7)) * 8);
    int vr = p * 64 + vrow;
    vdst[p] = vr * 64 + (((lane & 7) ^ (vr & 7)) * 8);
  }

  short8 kreg[2], vreg[2];
  auto issue = [&](int kvb) {
#pragma unroll
    for (int p = 0; p < 2; ++p)
      kreg[p] = *(const short8*)&kp[headq + (size_t)(kvb + p * 32 + krow) * Dc + kcol];
#pragma unroll
    for (int p = 0; p < 2; ++p)
      vreg[p] = *(const short8*)&vt[vbase + (size_t)(p * 64 + vrow) * Sc + kvb + vcol];
  };
  auto commit = [&]() {
#pragma unroll
    for (int p = 0; p < 2; ++p) *(short8*)&Ks[kdst[p]] = kreg[p];
#pragma unroll
    for (int p = 0; p < 2; ++p) *(short8*)&Vs[vdst[p]] = vreg[p];
  };

  issue(0);
  commit();
  __syncthreads();

  f32x4 o[2][8] = {};
  float mrun[2] = {-1e30f, -1e30f}, lrun[2] = {0.f, 0.f};
  const int ntiles = qb / 64 + 4;

  for (int t = 0; t < ntiles; ++t) {
    const bool active = (64 * t <= qw + 31);  // wave-uniform
    f32x4 sc[2][4];

    if (active) {
      __builtin_amdgcn_s_setprio(1);
#pragma unroll
      for (int nb = 0; nb < 4; ++nb) {
        f32x4 s0 = {}, s1 = {};
#pragma unroll
        for (int c = 0; c < 4; ++c) {
          short8 kf = *(const short8*)&Ks[(nb * 16 + lr) * 128 + (((c * 4 + g) ^ x7) << 3)];
          s0 = __builtin_amdgcn_mfma_f32_16x16x32_bf16(kf, qf[0][c], s0, 0, 0, 0);
          s1 = __builtin_amdgcn_mfma_f32_16x16x32_bf16(kf, qf[1][c], s1, 0, 0, 0);
        }
        sc[0][nb] = s0;
        sc[1][nb] = s1;
      }
      __builtin_amdgcn_s_setprio(0);
    }

    if (t + 1 < ntiles) issue((t + 1) * 64);  // prefetch hides under softmax+PV

    if (active) {
      const bool domask = (64 * t + 63 > qw);
#pragma unroll
      for (int qs = 0; qs < 2; ++qs) {
        const int qg = qw + qs * 16 + lr;
        float mnb[4];
#pragma unroll
        for (int nb = 0; nb < 4; ++nb) {
#pragma unroll
          for (int r = 0; r < 4; ++r) {
            float v = sc[qs][nb][r] * SCALE2;
            if (domask) {
              int kv = t * 64 + nb * 16 + rowl + r;
              v = (kv > qg) ? -1e30f : v;
            }
            sc[qs][nb][r] = v;
          }
          mnb[nb] = fmaxf(fmaxf(sc[qs][nb][0], sc[qs][nb][1]),
                          fmaxf(sc[qs][nb][2], sc[qs][nb][3]));
        }
        float mt = fmaxf(fmaxf(mnb[0], mnb[1]), fmaxf(mnb[2], mnb[3]));
        mt = fmaxf(mt, __shfl_xor(mt, 16));
        mt = fmaxf(mt, __shfl_xor(mt, 32));

        float mnew = fmaxf(mrun[qs], mt);
        float alpha = exp2s(mrun[qs] - mnew);
        mrun[qs] = mnew;

        float lsnb[4];
#pragma unroll
        for (int nb = 0; nb < 4; ++nb) {
          float p0 = exp2s(sc[qs][nb][0] - mnew);
          float p1 = exp2s(sc[qs][nb][1] - mnew);
          float p2 = exp2s(sc[qs][nb][2] - mnew);
          float p3 = exp2s(sc[qs][nb][3] - mnew);
          lsnb[nb] = (p0 + p1) + (p2 + p3);
          uint2 w;
          w.x = pack2(p0, p1);
          w.y = pack2(p2, p3);
          *(uint2*)&Ps[wid][qs * 16 + lr][nb * 16 + rowl] = w;
        }
        float ls = (lsnb[0] + lsnb[1]) + (lsnb[2] + lsnb[3]);
        ls += __shfl_xor(ls, 16);
        ls += __shfl_xor(ls, 32);
        lrun[qs] = lrun[qs] * alpha + ls;

        float al[4];
#pragma unroll
        for (int r = 0; r < 4; ++r) al[r] = __shfl(alpha, (lane & 48) | (rowl + r));
#pragma unroll
        for (int f = 0; f < 8; ++f)
#pragma unroll
          for (int r = 0; r < 4; ++r) o[qs][f][r] *= al[r];
      }

      asm volatile("s_waitcnt lgkmcnt(0)" ::: "memory");
      __builtin_amdgcn_sched_barrier(0);

      __builtin_amdgcn_s_setprio(1);
#pragma unroll
      for (int kc = 0; kc < 2; ++kc) {
        short8 pf0 = *(const short8*)&Ps[wid][lr][kc * 32 + lk];
        short8 pf1 = *(const short8*)&Ps[wid][16 + lr][kc * 32 + lk];
#pragma unroll
        for (int nb = 0; nb < 8; ++nb) {
          short8 vf = *(const short8*)&Vs[(nb * 16 + lr) * 64 + (((kc * 4 + g) ^ x7) << 3)];
          o[0][nb] = __builtin_amdgcn_mfma_f32_16x16x32_bf16(pf0, vf, o[0][nb], 0, 0, 0);
          o[1][nb] = __builtin_amdgcn_mfma_f32_16x16x32_bf16(pf1, vf, o[1][nb], 0, 0, 0);
        }
      }
      __builtin_amdgcn_s_setprio(0);
    }

    __syncthreads();               // all Ks/Vs reads of tile t done
    if (t + 1 < ntiles) commit();  // vmcnt auto-wait + ds_write
    __syncthreads();               // tile t+1 visible
  }

#pragma unroll
  for (int qs = 0; qs < 2; ++qs) {
    float ld[4];
#pragma unroll
    for (int r = 0; r < 4; ++r) ld[r] = __shfl(lrun[qs], (lane & 48) | (rowl + r));
#pragma unroll
    for (int f = 0; f < 8; ++f)
#pragma unroll
      for (int r = 0; r < 4; ++r) {
        float v = o[qs][f][r] / ld[r];
        attn[headq + (size_t)(qw + qs * 16 + rowl + r) * Dc + f * 16 + lr] = f2bf(v);
      }
  }
}

// ---------------------------------------------------------------------------
extern "C" void kernel_launch(void* const* d_in, const int* in_sizes, int n_in,
                              void* d_out, int out_size, void* d_ws, size_t ws_size,
                              hipStream_t stream) {
  const float* Q = (const float*)d_in[0];
  const float* K = (const float*)d_in[1];
  const float* V = (const float*)d_in[2];
  // d_in[3] = mask (causal tril, structural — unused)
  const float* wq = (const float*)d_in[4];
  const float* bq = (const float*)d_in[5];
  const float* wk = (const float*)d_in[6];
  const float* bk = (const float*)d_in[7];
  const float* wv = (const float*)d_in[8];
  const float* bv = (const float*)d_in[9];
  const float* wo = (const float*)d_in[10];
  const float* bo = (const float*)d_in[11];

  char* ws = (char*)d_ws;
  const size_t WSZ = (size_t)Dc * Dc;
  const size_t XSZ = (size_t)Bc * Sc * Dc;
  short* WT = (short*)ws;
  short* QP = (short*)(ws + 4 * WSZ * 2);
  short* KP = (short*)(ws + 4 * WSZ * 2 + XSZ * 2);
  short* VT = (short*)(ws + 4 * WSZ * 2 + 2 * XSZ * 2);
  short* AT = (short*)(ws + 4 * WSZ * 2 + 3 * XSZ * 2);  // scratch: conv in, attn out
  // total: 8*WSZ + 8*XSZ bytes = 32 MiB + 128 MiB = 160 MiB

  transpose_w_kernel<<<dim3(Dc / 32, Dc / 32, 4), 256, 0, stream>>>(wq, wk, wv, wo, WT);

  const int n8 = (int)(XSZ / 8);
  const int ng = (Bc * Sc / 256) * (Dc / 256);  // 32*8 = 256 blocks

  convert_kernel<<<2048, 256, 0, stream>>>(Q, AT, n8);
  gemm_ring_kernel<0><<<ng, 512, 0, stream>>>(AT, WT, bq, QP);
  convert_kernel<<<2048, 256, 0, stream>>>(K, AT, n8);
  gemm_ring_kernel<0><<<ng, 512, 0, stream>>>(AT, WT + WSZ, bk, KP);
  convert_kernel<<<2048, 256, 0, stream>>>(V, AT, n8);
  gemm_ring_kernel<2><<<ng, 512, 0, stream>>>(AT, WT + 2 * WSZ, bv, VT);

  attn_kernel<<<512, 512, 0, stream>>>(QP, KP, VT, AT);

  gemm_ring_kernel<1><<<ng, 512, 0, stream>>>(AT, WT + 3 * WSZ, bo, (float*)d_out);
}